// Round 1
// baseline (5228.722 us; speedup 1.0000x reference)
//
#include <hip/hip_runtime.h>

// SAGEConv: out = (mean_{j in N(i)} x_j) @ W_l + b_l + x_i @ W_r
// Inputs: x [N,128] f32, edge_index [2,E] int, W_l [128,128] f32, b_l [128] f32, W_r [128,128] f32
// Output: [N,128] f32

constexpr int N_NODES = 100000;
constexpr int N_EDGES = 625000;
constexpr int D = 128;
constexpr int TILE_ROWS = 32;

// ---------------- scatter: agg[dst] += x[src], deg[dst] += 1 ----------------
__global__ __launch_bounds__(256) void sage_scatter(
    const float* __restrict__ x,
    const int* __restrict__ src,
    const int* __restrict__ dst,
    float* __restrict__ agg,
    float* __restrict__ deg)
{
    int gid = blockIdx.x * 256 + threadIdx.x;
    int e = gid >> 7;          // 128 threads per edge
    if (e >= N_EDGES) return;
    int d = gid & 127;
    int s = src[e];
    int t = dst[e];
    atomicAdd(&agg[(size_t)t * D + d], x[(size_t)s * D + d]);
    if (d == 0) atomicAdd(&deg[t], 1.0f);
}

// ---------------- fused GEMM: out = mean @ Wl + b + x @ Wr (in-place on agg) --
__device__ __forceinline__ void accum_tile(
    float acc[4][4], const float (*sW)[D], const float (*srow)[D],
    int h, int j4)
{
    #pragma unroll
    for (int k = 0; k < D; k += 4) {
        float4 w0 = *(const float4*)&sW[k + 0][j4];
        float4 w1 = *(const float4*)&sW[k + 1][j4];
        float4 w2 = *(const float4*)&sW[k + 2][j4];
        float4 w3 = *(const float4*)&sW[k + 3][j4];
        #pragma unroll
        for (int r = 0; r < 4; ++r) {
            float4 a = *(const float4*)&srow[h + r * 8][k];
            acc[r][0] += a.x * w0.x + a.y * w1.x + a.z * w2.x + a.w * w3.x;
            acc[r][1] += a.x * w0.y + a.y * w1.y + a.z * w2.y + a.w * w3.y;
            acc[r][2] += a.x * w0.z + a.y * w1.z + a.z * w2.z + a.w * w3.z;
            acc[r][3] += a.x * w0.w + a.y * w1.w + a.z * w2.w + a.w * w3.w;
        }
    }
}

__global__ __launch_bounds__(256) void sage_gemm(
    const float* __restrict__ x,
    const float* __restrict__ Wl,
    const float* __restrict__ bl,
    const float* __restrict__ Wr,
    const float* __restrict__ deg,
    float* __restrict__ out)   // holds agg on entry; result on exit (in-place)
{
    __shared__ float sW[D][D];            // 64 KB, reused for Wl then Wr
    __shared__ float srow[TILE_ROWS][D];  // 16 KB row staging

    const int tid = threadIdx.x;
    const int j4 = (tid & 31) * 4;   // output column group
    const int h  = tid >> 5;         // 0..7 row phase
    const int nTiles = (N_NODES + TILE_ROWS - 1) / TILE_ROWS;

    const float4 bias = *(const float4*)(bl + j4);

    for (int tile = blockIdx.x; tile < nTiles; tile += gridDim.x) {
        const int row0 = tile * TILE_ROWS;
        float acc[4][4];
        #pragma unroll
        for (int r = 0; r < 4; ++r)
            #pragma unroll
            for (int c = 0; c < 4; ++c) acc[r][c] = 0.0f;

        // ---- phase 1: stage Wl + scaled mean rows ----
        __syncthreads();   // previous iteration readers done
        #pragma unroll
        for (int i = 0; i < 16; ++i) {
            int idx = tid + i * 256;  // float4 index into 128x128
            ((float4*)sW)[idx] = ((const float4*)Wl)[idx];
        }
        #pragma unroll
        for (int i = 0; i < 4; ++i) {
            int idx = tid + i * 256;      // float4 index into 32x128
            int r = idx >> 5;             // 32 float4 per row
            int c = idx & 31;
            int row = row0 + r;
            float4 v = make_float4(0.f, 0.f, 0.f, 0.f);
            if (row < N_NODES) {
                v = ((const float4*)out)[(size_t)row * 32 + c];
                float sc = 1.0f / fmaxf(deg[row], 1.0f);
                v.x *= sc; v.y *= sc; v.z *= sc; v.w *= sc;
            }
            ((float4*)srow)[idx] = v;
        }
        __syncthreads();
        accum_tile(acc, sW, srow, h, j4);

        // ---- phase 2: stage Wr + x rows ----
        __syncthreads();
        #pragma unroll
        for (int i = 0; i < 16; ++i) {
            int idx = tid + i * 256;
            ((float4*)sW)[idx] = ((const float4*)Wr)[idx];
        }
        #pragma unroll
        for (int i = 0; i < 4; ++i) {
            int idx = tid + i * 256;
            int r = idx >> 5;
            int c = idx & 31;
            int row = row0 + r;
            float4 v = make_float4(0.f, 0.f, 0.f, 0.f);
            if (row < N_NODES)
                v = ((const float4*)x)[(size_t)row * 32 + c];
            ((float4*)srow)[idx] = v;
        }
        __syncthreads();
        accum_tile(acc, sW, srow, h, j4);

        // ---- epilogue: bias + write (in-place over agg rows of this tile) ----
        #pragma unroll
        for (int r = 0; r < 4; ++r) {
            int row = row0 + h + r * 8;
            if (row < N_NODES) {
                float4 v = make_float4(acc[r][0] + bias.x,
                                       acc[r][1] + bias.y,
                                       acc[r][2] + bias.z,
                                       acc[r][3] + bias.w);
                *(float4*)(out + (size_t)row * D + j4) = v;
            }
        }
    }
}

extern "C" void kernel_launch(void* const* d_in, const int* in_sizes, int n_in,
                              void* d_out, int out_size, void* d_ws, size_t ws_size,
                              hipStream_t stream) {
    const float* x   = (const float*)d_in[0];
    const int*   ei  = (const int*)d_in[1];     // [2, E] int32
    const float* Wl  = (const float*)d_in[2];
    const float* bl  = (const float*)d_in[3];
    const float* Wr  = (const float*)d_in[4];
    float* out = (float*)d_out;
    float* deg = (float*)d_ws;                  // N floats

    const int* src = ei;
    const int* dst = ei + N_EDGES;

    // zero agg (in d_out) and deg
    hipMemsetAsync(out, 0, (size_t)N_NODES * D * sizeof(float), stream);
    hipMemsetAsync(deg, 0, (size_t)N_NODES * sizeof(float), stream);

    // scatter-add: 128 threads per edge
    {
        long long total = (long long)N_EDGES * 128;
        int blocks = (int)((total + 255) / 256);
        sage_scatter<<<blocks, 256, 0, stream>>>(x, src, dst, out, deg);
    }

    // fused dual-GEMM, in-place on d_out
    sage_gemm<<<512, 256, 0, stream>>>(x, Wl, bl, Wr, deg, out);
}

// Round 2
// 419.870 us; speedup vs baseline: 12.4532x; 12.4532x over previous
//
#include <hip/hip_runtime.h>

// SAGEConv: out = (mean_{j in N(i)} x_j) @ W_l + b_l + x_i @ W_r
// Inputs: x [N,128] f32, edge_index [2,E] int, W_l [128,128] f32, b_l [128] f32, W_r [128,128] f32
// Output: [N,128] f32

constexpr int N_NODES = 100000;
constexpr int N_EDGES = 625000;
constexpr int D = 128;
constexpr int TILE_ROWS = 32;

// ---------------- scatter: agg[dst] += x[src], deg[dst] += 1 ----------------
__global__ __launch_bounds__(256) void sage_scatter(
    const float* __restrict__ x,
    const int* __restrict__ src,
    const int* __restrict__ dst,
    float* __restrict__ agg,
    float* __restrict__ deg)
{
    int gid = blockIdx.x * 256 + threadIdx.x;
    int e = gid >> 7;          // 128 threads per edge
    if (e >= N_EDGES) return;
    int d = gid & 127;
    int s = src[e];
    int t = dst[e];
    atomicAdd(&agg[(size_t)t * D + d], x[(size_t)s * D + d]);
    if (d == 0) atomicAdd(&deg[t], 1.0f);
}

// ---------------- fused GEMM: out = mean @ Wl + b + x @ Wr (in-place on agg) --
// Low-register accumulate: only 4 w-float4 + 1 a-float4 live at a time.
__device__ __forceinline__ void accum_tile(
    float acc[4][4], const float (*sW)[D], const float (*srow)[D],
    int h, int j4)
{
    #pragma unroll 2
    for (int k = 0; k < D; k += 4) {
        float4 w0 = *(const float4*)&sW[k + 0][j4];
        float4 w1 = *(const float4*)&sW[k + 1][j4];
        float4 w2 = *(const float4*)&sW[k + 2][j4];
        float4 w3 = *(const float4*)&sW[k + 3][j4];
        #pragma unroll
        for (int r = 0; r < 4; ++r) {
            float4 a = *(const float4*)&srow[h + r * 8][k];
            acc[r][0] = fmaf(a.x, w0.x, fmaf(a.y, w1.x, fmaf(a.z, w2.x, fmaf(a.w, w3.x, acc[r][0]))));
            acc[r][1] = fmaf(a.x, w0.y, fmaf(a.y, w1.y, fmaf(a.z, w2.y, fmaf(a.w, w3.y, acc[r][1]))));
            acc[r][2] = fmaf(a.x, w0.z, fmaf(a.y, w1.z, fmaf(a.z, w2.z, fmaf(a.w, w3.z, acc[r][2]))));
            acc[r][3] = fmaf(a.x, w0.w, fmaf(a.y, w1.w, fmaf(a.z, w2.w, fmaf(a.w, w3.w, acc[r][3]))));
        }
    }
}

__global__ __launch_bounds__(256) void sage_gemm(
    const float* __restrict__ x,
    const float* __restrict__ Wl,
    const float* __restrict__ bl,
    const float* __restrict__ Wr,
    const float* __restrict__ deg,
    float* __restrict__ out)   // holds agg on entry; result on exit (in-place)
{
    __shared__ float sW[D][D];            // 64 KB, reused for Wl then Wr
    __shared__ float srow[TILE_ROWS][D];  // 16 KB row staging

    const int tid = threadIdx.x;
    const int j4 = (tid & 31) * 4;   // output column group
    const int h  = tid >> 5;         // 0..7 row phase
    const int nTiles = (N_NODES + TILE_ROWS - 1) / TILE_ROWS;

    const float4 bias = *(const float4*)(bl + j4);

    for (int tile = blockIdx.x; tile < nTiles; tile += gridDim.x) {
        const int row0 = tile * TILE_ROWS;
        float acc[4][4];
        #pragma unroll
        for (int r = 0; r < 4; ++r)
            #pragma unroll
            for (int c = 0; c < 4; ++c) acc[r][c] = 0.0f;

        // ---- phase 1: stage Wl + scaled mean rows ----
        __syncthreads();   // previous iteration readers done
        #pragma unroll
        for (int i = 0; i < 16; ++i) {
            int idx = tid + i * 256;  // float4 index into 128x128
            ((float4*)sW)[idx] = ((const float4*)Wl)[idx];
        }
        #pragma unroll
        for (int i = 0; i < 4; ++i) {
            int idx = tid + i * 256;      // float4 index into 32x128
            int r = idx >> 5;             // 32 float4 per row
            int c = idx & 31;
            int row = row0 + r;
            float4 v = make_float4(0.f, 0.f, 0.f, 0.f);
            if (row < N_NODES) {
                v = ((const float4*)out)[(size_t)row * 32 + c];
                float sc = 1.0f / fmaxf(deg[row], 1.0f);
                v.x *= sc; v.y *= sc; v.z *= sc; v.w *= sc;
            }
            ((float4*)srow)[idx] = v;
        }
        __syncthreads();
        accum_tile(acc, sW, srow, h, j4);

        // ---- phase 2: stage Wr + x rows ----
        __syncthreads();
        #pragma unroll
        for (int i = 0; i < 16; ++i) {
            int idx = tid + i * 256;
            ((float4*)sW)[idx] = ((const float4*)Wr)[idx];
        }
        #pragma unroll
        for (int i = 0; i < 4; ++i) {
            int idx = tid + i * 256;
            int r = idx >> 5;
            int c = idx & 31;
            int row = row0 + r;
            float4 v = make_float4(0.f, 0.f, 0.f, 0.f);
            if (row < N_NODES)
                v = ((const float4*)x)[(size_t)row * 32 + c];
            ((float4*)srow)[idx] = v;
        }
        __syncthreads();
        accum_tile(acc, sW, srow, h, j4);

        // ---- epilogue: bias + write (in-place over agg rows of this tile) ----
        #pragma unroll
        for (int r = 0; r < 4; ++r) {
            int row = row0 + h + r * 8;
            if (row < N_NODES) {
                float4 v = make_float4(acc[r][0] + bias.x,
                                       acc[r][1] + bias.y,
                                       acc[r][2] + bias.z,
                                       acc[r][3] + bias.w);
                *(float4*)(out + (size_t)row * D + j4) = v;
            }
        }
    }
}

extern "C" void kernel_launch(void* const* d_in, const int* in_sizes, int n_in,
                              void* d_out, int out_size, void* d_ws, size_t ws_size,
                              hipStream_t stream) {
    const float* x   = (const float*)d_in[0];
    const int*   ei  = (const int*)d_in[1];     // [2, E] int32
    const float* Wl  = (const float*)d_in[2];
    const float* bl  = (const float*)d_in[3];
    const float* Wr  = (const float*)d_in[4];
    float* out = (float*)d_out;
    float* deg = (float*)d_ws;                  // N floats

    const int* src = ei;
    const int* dst = ei + N_EDGES;

    // zero agg (in d_out) and deg
    hipMemsetAsync(out, 0, (size_t)N_NODES * D * sizeof(float), stream);
    hipMemsetAsync(deg, 0, (size_t)N_NODES * sizeof(float), stream);

    // scatter-add: 128 threads per edge
    {
        long long total = (long long)N_EDGES * 128;
        int blocks = (int)((total + 255) / 256);
        sage_scatter<<<blocks, 256, 0, stream>>>(x, src, dst, out, deg);
    }

    // fused dual-GEMM, in-place on d_out
    sage_gemm<<<512, 256, 0, stream>>>(x, Wl, bl, Wr, deg, out);
}

// Round 3
// 247.230 us; speedup vs baseline: 21.1492x; 1.6983x over previous
//
#include <hip/hip_runtime.h>

// SAGEConv: out = (mean_{j in N(i)} x_j) @ W_l + b_l + x_i @ W_r
// Inputs: x [N,128] f32, edge_index [2,E] int32, W_l [128,128] f32, b_l [128] f32, W_r [128,128] f32
// Output: [N,128] f32
//
// Strategy: build CSR (by dst) on device each call -> per-node wave gather-mean
// (no float atomics) -> fused dual-GEMM with W in LDS.

constexpr int N_NODES = 100000;
constexpr int N_EDGES = 625000;
constexpr int D = 128;
constexpr int TILE_ROWS = 32;
constexpr int SCAN_CHUNK = 1024;                 // elements per scan block
constexpr int N_SCAN_BLOCKS = (N_NODES + SCAN_CHUNK - 1) / SCAN_CHUNK;  // 98

// ================= CSR build =================
__global__ __launch_bounds__(256) void csr_hist(
    const int* __restrict__ dst, int* __restrict__ cnt)
{
    int e = blockIdx.x * 256 + threadIdx.x;
    if (e < N_EDGES) atomicAdd(&cnt[dst[e]], 1);
}

__global__ __launch_bounds__(256) void scan_blocks(
    const int* __restrict__ cnt, int* __restrict__ ptr, int* __restrict__ bsums)
{
    __shared__ int sh[256];
    const int t = threadIdx.x;
    const int base = blockIdx.x * SCAN_CHUNK + t * 4;
    int v0 = (base + 0 < N_NODES) ? cnt[base + 0] : 0;
    int v1 = (base + 1 < N_NODES) ? cnt[base + 1] : 0;
    int v2 = (base + 2 < N_NODES) ? cnt[base + 2] : 0;
    int v3 = (base + 3 < N_NODES) ? cnt[base + 3] : 0;
    const int tsum = v0 + v1 + v2 + v3;
    sh[t] = tsum;
    __syncthreads();
    // inclusive Hillis-Steele over 256 thread sums
    #pragma unroll
    for (int off = 1; off < 256; off <<= 1) {
        int val = (t >= off) ? sh[t - off] : 0;
        __syncthreads();
        sh[t] += val;
        __syncthreads();
    }
    const int texcl = sh[t] - tsum;
    if (t == 255) bsums[blockIdx.x] = sh[255];
    int e0 = texcl;
    int e1 = e0 + v0;
    int e2 = e1 + v1;
    int e3 = e2 + v2;
    if (base + 0 < N_NODES) ptr[base + 0] = e0;
    if (base + 1 < N_NODES) ptr[base + 1] = e1;
    if (base + 2 < N_NODES) ptr[base + 2] = e2;
    if (base + 3 < N_NODES) ptr[base + 3] = e3;
}

__global__ __launch_bounds__(128) void scan_bsums(int* __restrict__ bsums)
{
    __shared__ int sh[128];
    const int t = threadIdx.x;
    int v = (t < N_SCAN_BLOCKS) ? bsums[t] : 0;
    sh[t] = v;
    __syncthreads();
    #pragma unroll
    for (int off = 1; off < 128; off <<= 1) {
        int val = (t >= off) ? sh[t - off] : 0;
        __syncthreads();
        sh[t] += val;
        __syncthreads();
    }
    if (t < N_SCAN_BLOCKS) bsums[t] = sh[t] - v;   // exclusive
}

__global__ __launch_bounds__(256) void add_offsets(
    int* __restrict__ ptr, int* __restrict__ cursor, const int* __restrict__ bsums)
{
    int i = blockIdx.x * 256 + threadIdx.x;
    if (i < N_NODES) {
        int p = ptr[i] + bsums[i >> 10];
        ptr[i] = p;
        cursor[i] = p;
    }
    if (i == 0) ptr[N_NODES] = N_EDGES;
}

__global__ __launch_bounds__(256) void csr_fill(
    const int* __restrict__ src, const int* __restrict__ dst,
    int* __restrict__ cursor, int* __restrict__ sorted_src)
{
    int e = blockIdx.x * 256 + threadIdx.x;
    if (e < N_EDGES) {
        int t = dst[e];
        int pos = atomicAdd(&cursor[t], 1);
        sorted_src[pos] = src[e];
    }
}

// ================= gather-mean: one wave per node =================
__global__ __launch_bounds__(256) void sage_aggregate(
    const float* __restrict__ x,
    const int* __restrict__ ptr,
    const int* __restrict__ sorted_src,
    float* __restrict__ mean)    // [N, 128]
{
    const int node = blockIdx.x * 4 + (threadIdx.x >> 6);
    if (node >= N_NODES) return;
    const int lane = threadIdx.x & 63;
    const int beg = ptr[node];
    const int end = ptr[node + 1];

    float2 acc0 = make_float2(0.f, 0.f);
    float2 acc1 = make_float2(0.f, 0.f);
    int i = beg;
    for (; i + 1 < end; i += 2) {
        int s0 = sorted_src[i];
        int s1 = sorted_src[i + 1];
        float2 a = *(const float2*)&x[(size_t)s0 * D + lane * 2];
        float2 b = *(const float2*)&x[(size_t)s1 * D + lane * 2];
        acc0.x += a.x; acc0.y += a.y;
        acc1.x += b.x; acc1.y += b.y;
    }
    if (i < end) {
        int s0 = sorted_src[i];
        float2 a = *(const float2*)&x[(size_t)s0 * D + lane * 2];
        acc0.x += a.x; acc0.y += a.y;
    }
    const float sc = 1.0f / fmaxf((float)(end - beg), 1.0f);
    float2 r = make_float2((acc0.x + acc1.x) * sc, (acc0.y + acc1.y) * sc);
    *(float2*)&mean[(size_t)node * D + lane * 2] = r;
}

// ================= fallback scatter path (small ws) =================
__global__ __launch_bounds__(256) void sage_scatter(
    const float* __restrict__ x,
    const int* __restrict__ src,
    const int* __restrict__ dst,
    float* __restrict__ agg,
    float* __restrict__ deg)
{
    int gid = blockIdx.x * 256 + threadIdx.x;
    int e = gid >> 7;
    if (e >= N_EDGES) return;
    int d = gid & 127;
    int s = src[e];
    int t = dst[e];
    atomicAdd(&agg[(size_t)t * D + d], x[(size_t)s * D + d]);
    if (d == 0) atomicAdd(&deg[t], 1.0f);
}

__global__ __launch_bounds__(256) void apply_mean(
    float* __restrict__ agg, const float* __restrict__ deg)
{
    int gid = blockIdx.x * 256 + threadIdx.x;   // one float4 per thread
    int row = gid >> 5;
    if (row >= N_NODES) return;
    float sc = 1.0f / fmaxf(deg[row], 1.0f);
    float4 v = ((float4*)agg)[gid];
    v.x *= sc; v.y *= sc; v.z *= sc; v.w *= sc;
    ((float4*)agg)[gid] = v;
}

// ================= fused GEMM: out = mean @ Wl + b + x @ Wr ==========
__device__ __forceinline__ void accum_tile(
    float acc[4][4], const float (*sW)[D], const float (*srow)[D],
    int h, int j4)
{
    #pragma unroll 2
    for (int k = 0; k < D; k += 4) {
        float4 w0 = *(const float4*)&sW[k + 0][j4];
        float4 w1 = *(const float4*)&sW[k + 1][j4];
        float4 w2 = *(const float4*)&sW[k + 2][j4];
        float4 w3 = *(const float4*)&sW[k + 3][j4];
        #pragma unroll
        for (int r = 0; r < 4; ++r) {
            float4 a = *(const float4*)&srow[h + r * 8][k];
            acc[r][0] = fmaf(a.x, w0.x, fmaf(a.y, w1.x, fmaf(a.z, w2.x, fmaf(a.w, w3.x, acc[r][0]))));
            acc[r][1] = fmaf(a.x, w0.y, fmaf(a.y, w1.y, fmaf(a.z, w2.y, fmaf(a.w, w3.y, acc[r][1]))));
            acc[r][2] = fmaf(a.x, w0.z, fmaf(a.y, w1.z, fmaf(a.z, w2.z, fmaf(a.w, w3.z, acc[r][2]))));
            acc[r][3] = fmaf(a.x, w0.w, fmaf(a.y, w1.w, fmaf(a.z, w2.w, fmaf(a.w, w3.w, acc[r][3]))));
        }
    }
}

__global__ __launch_bounds__(256) void sage_gemm(
    const float* __restrict__ x,
    const float* __restrict__ Wl,
    const float* __restrict__ bl,
    const float* __restrict__ Wr,
    float* __restrict__ out)   // holds mean on entry; result on exit (in-place)
{
    __shared__ float sW[D][D];            // 64 KB, reused for Wl then Wr
    __shared__ float srow[TILE_ROWS][D];  // 16 KB row staging

    const int tid = threadIdx.x;
    const int j4 = (tid & 31) * 4;
    const int h  = tid >> 5;
    const int nTiles = (N_NODES + TILE_ROWS - 1) / TILE_ROWS;

    const float4 bias = *(const float4*)(bl + j4);

    for (int tile = blockIdx.x; tile < nTiles; tile += gridDim.x) {
        const int row0 = tile * TILE_ROWS;
        float acc[4][4];
        #pragma unroll
        for (int r = 0; r < 4; ++r)
            #pragma unroll
            for (int c = 0; c < 4; ++c) acc[r][c] = 0.0f;

        // ---- phase 1: Wl + mean rows ----
        __syncthreads();
        #pragma unroll
        for (int i = 0; i < 16; ++i) {
            int idx = tid + i * 256;
            ((float4*)sW)[idx] = ((const float4*)Wl)[idx];
        }
        #pragma unroll
        for (int i = 0; i < 4; ++i) {
            int idx = tid + i * 256;
            int r = idx >> 5;
            int c = idx & 31;
            int row = row0 + r;
            float4 v = make_float4(0.f, 0.f, 0.f, 0.f);
            if (row < N_NODES)
                v = ((const float4*)out)[(size_t)row * 32 + c];
            ((float4*)srow)[idx] = v;
        }
        __syncthreads();
        accum_tile(acc, sW, srow, h, j4);

        // ---- phase 2: Wr + x rows ----
        __syncthreads();
        #pragma unroll
        for (int i = 0; i < 16; ++i) {
            int idx = tid + i * 256;
            ((float4*)sW)[idx] = ((const float4*)Wr)[idx];
        }
        #pragma unroll
        for (int i = 0; i < 4; ++i) {
            int idx = tid + i * 256;
            int r = idx >> 5;
            int c = idx & 31;
            int row = row0 + r;
            float4 v = make_float4(0.f, 0.f, 0.f, 0.f);
            if (row < N_NODES)
                v = ((const float4*)x)[(size_t)row * 32 + c];
            ((float4*)srow)[idx] = v;
        }
        __syncthreads();
        accum_tile(acc, sW, srow, h, j4);

        // ---- epilogue ----
        #pragma unroll
        for (int r = 0; r < 4; ++r) {
            int row = row0 + h + r * 8;
            if (row < N_NODES) {
                float4 v = make_float4(acc[r][0] + bias.x,
                                       acc[r][1] + bias.y,
                                       acc[r][2] + bias.z,
                                       acc[r][3] + bias.w);
                *(float4*)(out + (size_t)row * D + j4) = v;
            }
        }
    }
}

extern "C" void kernel_launch(void* const* d_in, const int* in_sizes, int n_in,
                              void* d_out, int out_size, void* d_ws, size_t ws_size,
                              hipStream_t stream) {
    const float* x   = (const float*)d_in[0];
    const int*   ei  = (const int*)d_in[1];     // [2, E] int32
    const float* Wl  = (const float*)d_in[2];
    const float* bl  = (const float*)d_in[3];
    const float* Wr  = (const float*)d_in[4];
    float* out = (float*)d_out;

    const int* src = ei;
    const int* dst = ei + N_EDGES;

    // workspace layout (ints)
    int* cnt    = (int*)d_ws;                    // N
    int* ptr    = cnt + N_NODES;                 // N+1
    int* cursor = ptr + N_NODES + 1;             // N
    int* bsums  = cursor + N_NODES;              // 128
    int* sorted = bsums + 128;                   // E
    size_t needed = (size_t)(3 * N_NODES + 1 + 128 + N_EDGES) * sizeof(int);

    if (ws_size >= needed) {
        // ---- CSR build ----
        hipMemsetAsync(cnt, 0, (size_t)N_NODES * sizeof(int), stream);
        csr_hist<<<(N_EDGES + 255) / 256, 256, 0, stream>>>(dst, cnt);
        scan_blocks<<<N_SCAN_BLOCKS, 256, 0, stream>>>(cnt, ptr, bsums);
        scan_bsums<<<1, 128, 0, stream>>>(bsums);
        add_offsets<<<(N_NODES + 255) / 256, 256, 0, stream>>>(ptr, cursor, bsums);
        csr_fill<<<(N_EDGES + 255) / 256, 256, 0, stream>>>(src, dst, cursor, sorted);
        // ---- gather mean (writes every row of out) ----
        sage_aggregate<<<(N_NODES + 3) / 4, 256, 0, stream>>>(x, ptr, sorted, out);
    } else {
        // fallback: atomic scatter path
        float* deg = (float*)d_ws;  // N floats
        hipMemsetAsync(out, 0, (size_t)N_NODES * D * sizeof(float), stream);
        hipMemsetAsync(deg, 0, (size_t)N_NODES * sizeof(float), stream);
        long long total = (long long)N_EDGES * 128;
        sage_scatter<<<(int)((total + 255) / 256), 256, 0, stream>>>(x, src, dst, out, deg);
        apply_mean<<<(N_NODES * 32 + 255) / 256, 256, 0, stream>>>(out, deg);
    }

    // ---- fused dual-GEMM, in-place on d_out ----
    sage_gemm<<<512, 256, 0, stream>>>(x, Wl, bl, Wr, out);
}

// Round 4
// 165.650 us; speedup vs baseline: 31.5648x; 1.4925x over previous
//
#include <hip/hip_runtime.h>

// SAGEConv: out = (mean_{j in N(i)} x_j) @ W_l + b_l + x_i @ W_r
// Inputs: x [N,128] f32, edge_index [2,E] int32, W_l [128,128] f32, b_l [128] f32, W_r [128,128] f32
// Output: [N,128] f32
//
// Pipeline: CSR build (counting sort) -> per-node wave gather-mean (fp32, into d_out)
//           -> W^T bf16 pre-transpose -> bf16 MFMA dual-GEMM (K=256), in-place on d_out.

constexpr int N_NODES = 100000;
constexpr int N_EDGES = 625000;
constexpr int D = 128;
constexpr int SCAN_CHUNK = 1024;
constexpr int N_SCAN_BLOCKS = (N_NODES + SCAN_CHUNK - 1) / SCAN_CHUNK;  // 98

typedef __attribute__((ext_vector_type(8))) short short8;
typedef __attribute__((ext_vector_type(4))) short short4v;
typedef __attribute__((ext_vector_type(4))) float f32x4;

__device__ __forceinline__ unsigned short f2bf(float f) {
    union { float f; unsigned int u; } c; c.f = f;
    unsigned int u = c.u + 0x7fffu + ((c.u >> 16) & 1u);   // RNE
    return (unsigned short)(u >> 16);
}

// ================= CSR build =================
__global__ __launch_bounds__(256) void csr_hist(
    const int* __restrict__ dst, int* __restrict__ cnt)
{
    int e = blockIdx.x * 256 + threadIdx.x;
    if (e < N_EDGES) atomicAdd(&cnt[dst[e]], 1);
}

__global__ __launch_bounds__(256) void scan_blocks(
    const int* __restrict__ cnt, int* __restrict__ ptr, int* __restrict__ bsums)
{
    __shared__ int sh[256];
    const int t = threadIdx.x;
    const int base = blockIdx.x * SCAN_CHUNK + t * 4;
    int v0 = (base + 0 < N_NODES) ? cnt[base + 0] : 0;
    int v1 = (base + 1 < N_NODES) ? cnt[base + 1] : 0;
    int v2 = (base + 2 < N_NODES) ? cnt[base + 2] : 0;
    int v3 = (base + 3 < N_NODES) ? cnt[base + 3] : 0;
    const int tsum = v0 + v1 + v2 + v3;
    sh[t] = tsum;
    __syncthreads();
    #pragma unroll
    for (int off = 1; off < 256; off <<= 1) {
        int val = (t >= off) ? sh[t - off] : 0;
        __syncthreads();
        sh[t] += val;
        __syncthreads();
    }
    const int texcl = sh[t] - tsum;
    if (t == 255) bsums[blockIdx.x] = sh[255];
    int e0 = texcl, e1 = e0 + v0, e2 = e1 + v1, e3 = e2 + v2;
    if (base + 0 < N_NODES) ptr[base + 0] = e0;
    if (base + 1 < N_NODES) ptr[base + 1] = e1;
    if (base + 2 < N_NODES) ptr[base + 2] = e2;
    if (base + 3 < N_NODES) ptr[base + 3] = e3;
}

__global__ __launch_bounds__(128) void scan_bsums(int* __restrict__ bsums)
{
    __shared__ int sh[128];
    const int t = threadIdx.x;
    int v = (t < N_SCAN_BLOCKS) ? bsums[t] : 0;
    sh[t] = v;
    __syncthreads();
    #pragma unroll
    for (int off = 1; off < 128; off <<= 1) {
        int val = (t >= off) ? sh[t - off] : 0;
        __syncthreads();
        sh[t] += val;
        __syncthreads();
    }
    if (t < N_SCAN_BLOCKS) bsums[t] = sh[t] - v;
}

__global__ __launch_bounds__(256) void add_offsets(
    int* __restrict__ ptr, int* __restrict__ cursor, const int* __restrict__ bsums)
{
    int i = blockIdx.x * 256 + threadIdx.x;
    if (i < N_NODES) {
        int p = ptr[i] + bsums[i >> 10];
        ptr[i] = p;
        cursor[i] = p;
    }
    if (i == 0) ptr[N_NODES] = N_EDGES;
}

__global__ __launch_bounds__(256) void csr_fill(
    const int* __restrict__ src, const int* __restrict__ dst,
    int* __restrict__ cursor, int* __restrict__ sorted_src)
{
    int e = blockIdx.x * 256 + threadIdx.x;
    if (e < N_EDGES) {
        int t = dst[e];
        int pos = atomicAdd(&cursor[t], 1);
        sorted_src[pos] = src[e];
    }
}

// ================= gather-mean: one wave per node (fp32 mean -> d_out) ======
__global__ __launch_bounds__(256) void sage_aggregate(
    const float* __restrict__ x,
    const int* __restrict__ ptr,
    const int* __restrict__ sorted_src,
    float* __restrict__ mean)
{
    const int node = blockIdx.x * 4 + (threadIdx.x >> 6);
    if (node >= N_NODES) return;
    const int lane = threadIdx.x & 63;
    const int beg = ptr[node];
    const int end = ptr[node + 1];

    float2 acc0 = make_float2(0.f, 0.f);
    float2 acc1 = make_float2(0.f, 0.f);
    int i = beg;
    for (; i + 1 < end; i += 2) {
        int s0 = sorted_src[i];
        int s1 = sorted_src[i + 1];
        float2 a = *(const float2*)&x[(size_t)s0 * D + lane * 2];
        float2 b = *(const float2*)&x[(size_t)s1 * D + lane * 2];
        acc0.x += a.x; acc0.y += a.y;
        acc1.x += b.x; acc1.y += b.y;
    }
    if (i < end) {
        int s0 = sorted_src[i];
        float2 a = *(const float2*)&x[(size_t)s0 * D + lane * 2];
        acc0.x += a.x; acc0.y += a.y;
    }
    const float sc = 1.0f / fmaxf((float)(end - beg), 1.0f);
    float2 r = make_float2((acc0.x + acc1.x) * sc, (acc0.y + acc1.y) * sc);
    *(float2*)&mean[(size_t)node * D + lane * 2] = r;
}

// ================= W^T build: wT[n][k] bf16, k<128 -> Wl, k>=128 -> Wr ======
__global__ __launch_bounds__(256) void wt_build(
    const float* __restrict__ Wl, const float* __restrict__ Wr,
    unsigned short* __restrict__ wT)
{
    int idx = blockIdx.x * 256 + threadIdx.x;   // 0 .. 128*256-1
    if (idx >= 128 * 256) return;
    int n = idx >> 8;
    int k = idx & 255;
    float v = (k < 128) ? Wl[k * 128 + n] : Wr[(k - 128) * 128 + n];
    wT[n * 256 + k] = f2bf(v);
}

// ================= bf16 MFMA GEMM: out = [mean|x] @ wT^T + b (in-place) =====
// Tile: BM=32, BN=128 (full), K=256. Block = 256 thr (4 waves), wave w owns
// cols [w*32, w*32+32). LDS: sW[128][256] bf16 (persistent, XOR-swizzled) +
// sA[32][256] bf16. Swizzle: 16B slot u -> u ^ (row&7)  (row stride 512B).
__global__ __launch_bounds__(256) void sage_gemm_mfma(
    const float* __restrict__ x,
    const unsigned short* __restrict__ wT,
    const float* __restrict__ bl,
    float* __restrict__ out)    // mean on entry; result on exit
{
    __shared__ unsigned short sW[128 * 256];  // 64 KB
    __shared__ unsigned short sA[32 * 256];   // 16 KB

    const int tid  = threadIdx.x;
    const int lane = tid & 63;
    const int w    = tid >> 6;       // wave id 0..3
    const int l15  = lane & 15;
    const int lg   = lane >> 4;      // k-group 0..3

    // ---- stage W^T once (linear global read, swizzled LDS write) ----
    #pragma unroll
    for (int i = 0; i < 16; ++i) {
        int c  = tid + i * 256;          // ushort8 chunk id, 0..4095
        int n  = c >> 5;                 // 32 chunks per row
        int k8 = c & 31;                 // 16B slot within row
        short8 v = ((const short8*)wT)[c];
        *(short8*)&sW[n * 256 + ((k8 ^ (n & 7)) << 3)] = v;
    }

    const int a_r0 = l15;
    const int a_r1 = 16 + l15;
    const int n0 = w * 32 + l15;
    const int n1 = n0 + 16;
    const float bias0 = bl[n0];
    const float bias1 = bl[n1];

    const int nTiles = N_NODES / 32;   // 3125, exact

    for (int tile = blockIdx.x; tile < nTiles; tile += gridDim.x) {
        const int row0 = tile * 32;

        // ---- stage A: rows [row0,row0+32), k<128 = mean (from out), k>=128 = x
        #pragma unroll
        for (int i = 0; i < 8; ++i) {
            int c    = tid + i * 256;      // float4 chunk 0..2047
            int r    = c >> 6;             // 64 chunks per row
            int half = (c >> 5) & 1;
            int f4   = c & 31;
            const float* srcp = half ? &x[(size_t)(row0 + r) * D + f4 * 4]
                                     : &out[(size_t)(row0 + r) * D + f4 * 4];
            float4 v = *(const float4*)srcp;
            short4v b;
            b.x = (short)f2bf(v.x); b.y = (short)f2bf(v.y);
            b.z = (short)f2bf(v.z); b.w = (short)f2bf(v.w);
            int k = half * 128 + f4 * 4;
            int u = k >> 3;
            *(short4v*)&sA[r * 256 + ((u ^ (r & 7)) << 3) + (k & 7)] = b;
        }
        __syncthreads();   // sA (and sW on first iter) ready

        f32x4 acc00 = {0.f,0.f,0.f,0.f}, acc01 = {0.f,0.f,0.f,0.f};
        f32x4 acc10 = {0.f,0.f,0.f,0.f}, acc11 = {0.f,0.f,0.f,0.f};

        #pragma unroll
        for (int s = 0; s < 8; ++s) {
            int ks = s * 4 + lg;   // 16B slot index of this lane's k-chunk
            short8 a0 = *(const short8*)&sA[a_r0 * 256 + ((ks ^ (a_r0 & 7)) << 3)];
            short8 a1 = *(const short8*)&sA[a_r1 * 256 + ((ks ^ (a_r1 & 7)) << 3)];
            short8 b0 = *(const short8*)&sW[n0 * 256 + ((ks ^ (n0 & 7)) << 3)];
            short8 b1 = *(const short8*)&sW[n1 * 256 + ((ks ^ (n1 & 7)) << 3)];
            acc00 = __builtin_amdgcn_mfma_f32_16x16x32_bf16(a0, b0, acc00, 0, 0, 0);
            acc01 = __builtin_amdgcn_mfma_f32_16x16x32_bf16(a0, b1, acc01, 0, 0, 0);
            acc10 = __builtin_amdgcn_mfma_f32_16x16x32_bf16(a1, b0, acc10, 0, 0, 0);
            acc11 = __builtin_amdgcn_mfma_f32_16x16x32_bf16(a1, b1, acc11, 0, 0, 0);
        }
        __syncthreads();   // all reads done before next tile overwrites sA

        // ---- epilogue: C layout col=lane&15, row=(lane>>4)*4+reg (m89) ----
        #pragma unroll
        for (int reg = 0; reg < 4; ++reg) {
            int r0w = row0 + lg * 4 + reg;        // fr=0 rows
            int r1w = r0w + 16;                   // fr=1 rows
            out[(size_t)r0w * D + n0] = acc00[reg] + bias0;
            out[(size_t)r0w * D + n1] = acc01[reg] + bias1;
            out[(size_t)r1w * D + n0] = acc10[reg] + bias0;
            out[(size_t)r1w * D + n1] = acc11[reg] + bias1;
        }
    }
}

// ================= fallback path (tiny ws): scatter + fp32 GEMM ============
__global__ __launch_bounds__(256) void sage_scatter(
    const float* __restrict__ x, const int* __restrict__ src,
    const int* __restrict__ dst, float* __restrict__ agg, float* __restrict__ deg)
{
    int gid = blockIdx.x * 256 + threadIdx.x;
    int e = gid >> 7;
    if (e >= N_EDGES) return;
    int d = gid & 127;
    atomicAdd(&agg[(size_t)dst[e] * D + d], x[(size_t)src[e] * D + d]);
    if (d == 0) atomicAdd(&deg[dst[e]], 1.0f);
}

__global__ __launch_bounds__(256) void apply_mean(
    float* __restrict__ agg, const float* __restrict__ deg)
{
    int gid = blockIdx.x * 256 + threadIdx.x;
    int row = gid >> 5;
    if (row >= N_NODES) return;
    float sc = 1.0f / fmaxf(deg[row], 1.0f);
    float4 v = ((float4*)agg)[gid];
    v.x *= sc; v.y *= sc; v.z *= sc; v.w *= sc;
    ((float4*)agg)[gid] = v;
}

__device__ __forceinline__ void accum_tile(
    float acc[4][4], const float (*sWf)[D], const float (*srow)[D], int h, int j4)
{
    #pragma unroll 2
    for (int k = 0; k < D; k += 4) {
        float4 w0 = *(const float4*)&sWf[k + 0][j4];
        float4 w1 = *(const float4*)&sWf[k + 1][j4];
        float4 w2 = *(const float4*)&sWf[k + 2][j4];
        float4 w3 = *(const float4*)&sWf[k + 3][j4];
        #pragma unroll
        for (int r = 0; r < 4; ++r) {
            float4 a = *(const float4*)&srow[h + r * 8][k];
            acc[r][0] = fmaf(a.x, w0.x, fmaf(a.y, w1.x, fmaf(a.z, w2.x, fmaf(a.w, w3.x, acc[r][0]))));
            acc[r][1] = fmaf(a.x, w0.y, fmaf(a.y, w1.y, fmaf(a.z, w2.y, fmaf(a.w, w3.y, acc[r][1]))));
            acc[r][2] = fmaf(a.x, w0.z, fmaf(a.y, w1.z, fmaf(a.z, w2.z, fmaf(a.w, w3.z, acc[r][2]))));
            acc[r][3] = fmaf(a.x, w0.w, fmaf(a.y, w1.w, fmaf(a.z, w2.w, fmaf(a.w, w3.w, acc[r][3]))));
        }
    }
}

__global__ __launch_bounds__(256) void sage_gemm_f32(
    const float* __restrict__ x, const float* __restrict__ Wl,
    const float* __restrict__ bl, const float* __restrict__ Wr,
    float* __restrict__ out)
{
    __shared__ float sWf[D][D];
    __shared__ float srow[32][D];
    const int tid = threadIdx.x;
    const int j4 = (tid & 31) * 4;
    const int h  = tid >> 5;
    const int nTiles = (N_NODES + 31) / 32;
    const float4 bias = *(const float4*)(bl + j4);

    for (int tile = blockIdx.x; tile < nTiles; tile += gridDim.x) {
        const int row0 = tile * 32;
        float acc[4][4];
        #pragma unroll
        for (int r = 0; r < 4; ++r)
            #pragma unroll
            for (int c = 0; c < 4; ++c) acc[r][c] = 0.0f;

        __syncthreads();
        #pragma unroll
        for (int i = 0; i < 16; ++i)
            ((float4*)sWf)[tid + i * 256] = ((const float4*)Wl)[tid + i * 256];
        #pragma unroll
        for (int i = 0; i < 4; ++i) {
            int idx = tid + i * 256, r = idx >> 5, c = idx & 31, row = row0 + r;
            float4 v = make_float4(0.f,0.f,0.f,0.f);
            if (row < N_NODES) v = ((const float4*)out)[(size_t)row * 32 + c];
            ((float4*)srow)[idx] = v;
        }
        __syncthreads();
        accum_tile(acc, sWf, srow, h, j4);

        __syncthreads();
        #pragma unroll
        for (int i = 0; i < 16; ++i)
            ((float4*)sWf)[tid + i * 256] = ((const float4*)Wr)[tid + i * 256];
        #pragma unroll
        for (int i = 0; i < 4; ++i) {
            int idx = tid + i * 256, r = idx >> 5, c = idx & 31, row = row0 + r;
            float4 v = make_float4(0.f,0.f,0.f,0.f);
            if (row < N_NODES) v = ((const float4*)x)[(size_t)row * 32 + c];
            ((float4*)srow)[idx] = v;
        }
        __syncthreads();
        accum_tile(acc, sWf, srow, h, j4);

        #pragma unroll
        for (int r = 0; r < 4; ++r) {
            int row = row0 + h + r * 8;
            if (row < N_NODES) {
                float4 v = make_float4(acc[r][0] + bias.x, acc[r][1] + bias.y,
                                       acc[r][2] + bias.z, acc[r][3] + bias.w);
                *(float4*)(out + (size_t)row * D + j4) = v;
            }
        }
    }
}

extern "C" void kernel_launch(void* const* d_in, const int* in_sizes, int n_in,
                              void* d_out, int out_size, void* d_ws, size_t ws_size,
                              hipStream_t stream) {
    const float* x   = (const float*)d_in[0];
    const int*   ei  = (const int*)d_in[1];
    const float* Wl  = (const float*)d_in[2];
    const float* bl  = (const float*)d_in[3];
    const float* Wr  = (const float*)d_in[4];
    float* out = (float*)d_out;

    const int* src = ei;
    const int* dst = ei + N_EDGES;

    int* cnt    = (int*)d_ws;                    // N
    int* ptr    = cnt + N_NODES;                 // N+1
    int* cursor = ptr + N_NODES + 1;             // N  (reused as wT after csr_fill)
    int* bsums  = cursor + N_NODES;              // 128
    int* sorted = bsums + 128;                   // E
    size_t needed = (size_t)(3 * N_NODES + 1 + 128 + N_EDGES) * sizeof(int);

    if (ws_size >= needed) {
        hipMemsetAsync(cnt, 0, (size_t)N_NODES * sizeof(int), stream);
        csr_hist<<<(N_EDGES + 255) / 256, 256, 0, stream>>>(dst, cnt);
        scan_blocks<<<N_SCAN_BLOCKS, 256, 0, stream>>>(cnt, ptr, bsums);
        scan_bsums<<<1, 128, 0, stream>>>(bsums);
        add_offsets<<<(N_NODES + 255) / 256, 256, 0, stream>>>(ptr, cursor, bsums);
        csr_fill<<<(N_EDGES + 255) / 256, 256, 0, stream>>>(src, dst, cursor, sorted);

        // cursor is dead now -> reuse its 400KB as wT (needs 64KB)
        unsigned short* wT = (unsigned short*)cursor;
        wt_build<<<(128 * 256 + 255) / 256, 256, 0, stream>>>(Wl, Wr, wT);

        sage_aggregate<<<(N_NODES + 3) / 4, 256, 0, stream>>>(x, ptr, sorted, out);
        sage_gemm_mfma<<<512, 256, 0, stream>>>(x, wT, bl, out);
    } else {
        float* deg = (float*)d_ws;
        hipMemsetAsync(out, 0, (size_t)N_NODES * D * sizeof(float), stream);
        hipMemsetAsync(deg, 0, (size_t)N_NODES * sizeof(float), stream);
        long long total = (long long)N_EDGES * 128;
        sage_scatter<<<(int)((total + 255) / 256), 256, 0, stream>>>(x, src, dst, out, deg);
        apply_mean<<<(N_NODES * 32 + 255) / 256, 256, 0, stream>>>(out, deg);
        sage_gemm_f32<<<512, 256, 0, stream>>>(x, Wl, bl, Wr, out);
    }
}

// Round 5
// 154.235 us; speedup vs baseline: 33.9009x; 1.0740x over previous
//
#include <hip/hip_runtime.h>

// SAGEConv: out = (mean_{j in N(i)} x_j) @ W_l + b_l + x_i @ W_r
// Inputs: x [N,128] f32, edge_index [2,E] int32, W_l [128,128] f32, b_l [128] f32, W_r [128,128] f32
// Output: [N,128] f32
//
// Pipeline (Path A): CSR build -> x->bf16 (xb) -> bf16 gather-mean (4-way ILP, bf16 out)
//                    -> bf16 MFMA dual-GEMM (K=256) reading mean_bf + xb.
// Fallbacks: A' (fp32 mean in d_out, bf16 x), B (R4 all-fp32-staging), C (atomic scatter).

constexpr int N_NODES = 100000;
constexpr int N_EDGES = 625000;
constexpr int D = 128;
constexpr int SCAN_CHUNK = 1024;
constexpr int N_SCAN_BLOCKS = (N_NODES + SCAN_CHUNK - 1) / SCAN_CHUNK;  // 98

typedef __attribute__((ext_vector_type(8))) short short8;
typedef __attribute__((ext_vector_type(4))) short short4v;
typedef __attribute__((ext_vector_type(4))) float f32x4;

__device__ __forceinline__ unsigned short f2bf(float f) {
    union { float f; unsigned int u; } c; c.f = f;
    unsigned int u = c.u + 0x7fffu + ((c.u >> 16) & 1u);   // RNE
    return (unsigned short)(u >> 16);
}
__device__ __forceinline__ float bflo(unsigned int v) {
    union { unsigned int u; float f; } c; c.u = v << 16; return c.f;
}
__device__ __forceinline__ float bfhi(unsigned int v) {
    union { unsigned int u; float f; } c; c.u = v & 0xffff0000u; return c.f;
}

// ================= CSR build =================
__global__ __launch_bounds__(256) void csr_hist(
    const int* __restrict__ dst, int* __restrict__ cnt)
{
    int e = blockIdx.x * 256 + threadIdx.x;
    if (e < N_EDGES) atomicAdd(&cnt[dst[e]], 1);
}

__global__ __launch_bounds__(256) void scan_blocks(
    const int* __restrict__ cnt, int* __restrict__ ptr, int* __restrict__ bsums)
{
    __shared__ int sh[256];
    const int t = threadIdx.x;
    const int base = blockIdx.x * SCAN_CHUNK + t * 4;
    int v0 = (base + 0 < N_NODES) ? cnt[base + 0] : 0;
    int v1 = (base + 1 < N_NODES) ? cnt[base + 1] : 0;
    int v2 = (base + 2 < N_NODES) ? cnt[base + 2] : 0;
    int v3 = (base + 3 < N_NODES) ? cnt[base + 3] : 0;
    const int tsum = v0 + v1 + v2 + v3;
    sh[t] = tsum;
    __syncthreads();
    #pragma unroll
    for (int off = 1; off < 256; off <<= 1) {
        int val = (t >= off) ? sh[t - off] : 0;
        __syncthreads();
        sh[t] += val;
        __syncthreads();
    }
    const int texcl = sh[t] - tsum;
    if (t == 255) bsums[blockIdx.x] = sh[255];
    int e0 = texcl, e1 = e0 + v0, e2 = e1 + v1, e3 = e2 + v2;
    if (base + 0 < N_NODES) ptr[base + 0] = e0;
    if (base + 1 < N_NODES) ptr[base + 1] = e1;
    if (base + 2 < N_NODES) ptr[base + 2] = e2;
    if (base + 3 < N_NODES) ptr[base + 3] = e3;
}

__global__ __launch_bounds__(128) void scan_bsums(int* __restrict__ bsums)
{
    __shared__ int sh[128];
    const int t = threadIdx.x;
    int v = (t < N_SCAN_BLOCKS) ? bsums[t] : 0;
    sh[t] = v;
    __syncthreads();
    #pragma unroll
    for (int off = 1; off < 128; off <<= 1) {
        int val = (t >= off) ? sh[t - off] : 0;
        __syncthreads();
        sh[t] += val;
        __syncthreads();
    }
    if (t < N_SCAN_BLOCKS) bsums[t] = sh[t] - v;
}

__global__ __launch_bounds__(256) void add_offsets(
    int* __restrict__ ptr, int* __restrict__ cursor, const int* __restrict__ bsums)
{
    int i = blockIdx.x * 256 + threadIdx.x;
    if (i < N_NODES) {
        int p = ptr[i] + bsums[i >> 10];
        ptr[i] = p;
        cursor[i] = p;
    }
    if (i == 0) ptr[N_NODES] = N_EDGES;
}

__global__ __launch_bounds__(256) void csr_fill(
    const int* __restrict__ src, const int* __restrict__ dst,
    int* __restrict__ cursor, int* __restrict__ sorted_src)
{
    int e = blockIdx.x * 256 + threadIdx.x;
    if (e < N_EDGES) {
        int t = dst[e];
        int pos = atomicAdd(&cursor[t], 1);
        sorted_src[pos] = src[e];
    }
}

// ================= x -> bf16 =================
__global__ __launch_bounds__(256) void x2bf(
    const float* __restrict__ x, unsigned short* __restrict__ xb)
{
    int c = blockIdx.x * 256 + threadIdx.x;          // short8 chunk, N*D/8 total
    if (c >= N_NODES * D / 8) return;
    const float4* xp = (const float4*)x;
    float4 a = xp[(size_t)c * 2];
    float4 b = xp[(size_t)c * 2 + 1];
    short8 v;
    v[0] = (short)f2bf(a.x); v[1] = (short)f2bf(a.y);
    v[2] = (short)f2bf(a.z); v[3] = (short)f2bf(a.w);
    v[4] = (short)f2bf(b.x); v[5] = (short)f2bf(b.y);
    v[6] = (short)f2bf(b.z); v[7] = (short)f2bf(b.w);
    ((short8*)xb)[c] = v;
}

// ================= W^T build: wT[n][k] bf16, k<128 -> Wl, k>=128 -> Wr ======
__global__ __launch_bounds__(256) void wt_build(
    const float* __restrict__ Wl, const float* __restrict__ Wr,
    unsigned short* __restrict__ wT)
{
    int idx = blockIdx.x * 256 + threadIdx.x;
    if (idx >= 128 * 256) return;
    int n = idx >> 8;
    int k = idx & 255;
    float v = (k < 128) ? Wl[k * 128 + n] : Wr[(k - 128) * 128 + n];
    wT[n * 256 + k] = f2bf(v);
}

// ================= gather-mean from bf16 x, 4-way neighbor ILP ==============
template<bool MBF>
__global__ __launch_bounds__(256) void sage_aggregate_bf(
    const unsigned short* __restrict__ xb,
    const int* __restrict__ ptr,
    const int* __restrict__ sorted_src,
    unsigned short* __restrict__ mean_bf,
    float* __restrict__ mean_f32)
{
    const int node = blockIdx.x * 4 + (threadIdx.x >> 6);
    if (node >= N_NODES) return;
    const int lane = threadIdx.x & 63;
    const int beg = ptr[node];
    const int end = ptr[node + 1];
    const int off = lane * 2;

    float a0 = 0.f, a1 = 0.f, b0 = 0.f, b1 = 0.f;
    float c0 = 0.f, c1 = 0.f, d0 = 0.f, d1 = 0.f;
    int i = beg;
    for (; i + 3 < end; i += 4) {
        int s0 = sorted_src[i], s1 = sorted_src[i + 1];
        int s2 = sorted_src[i + 2], s3 = sorted_src[i + 3];
        unsigned int v0 = *(const unsigned int*)&xb[(size_t)s0 * D + off];
        unsigned int v1 = *(const unsigned int*)&xb[(size_t)s1 * D + off];
        unsigned int v2 = *(const unsigned int*)&xb[(size_t)s2 * D + off];
        unsigned int v3 = *(const unsigned int*)&xb[(size_t)s3 * D + off];
        a0 += bflo(v0); a1 += bfhi(v0);
        b0 += bflo(v1); b1 += bfhi(v1);
        c0 += bflo(v2); c1 += bfhi(v2);
        d0 += bflo(v3); d1 += bfhi(v3);
    }
    for (; i < end; ++i) {
        int s0 = sorted_src[i];
        unsigned int v0 = *(const unsigned int*)&xb[(size_t)s0 * D + off];
        a0 += bflo(v0); a1 += bfhi(v0);
    }
    const float sc = 1.0f / fmaxf((float)(end - beg), 1.0f);
    float r0 = ((a0 + b0) + (c0 + d0)) * sc;
    float r1 = ((a1 + b1) + (c1 + d1)) * sc;
    if (MBF) {
        unsigned int r = (unsigned int)f2bf(r0) | ((unsigned int)f2bf(r1) << 16);
        *(unsigned int*)&mean_bf[(size_t)node * D + off] = r;
    } else {
        *(float2*)&mean_f32[(size_t)node * D + off] = make_float2(r0, r1);
    }
}

// ================= bf16 MFMA GEMM (Path A / A') ============================
// BM=32, BN=128, K=256. 4 waves; wave w owns cols [w*32, w*32+32).
// sW[128][256] bf16 persistent + sA[32][256] bf16, both XOR-swizzled
// (16B slot u -> u ^ (row&7); row stride 512B).
template<bool MBF>
__global__ __launch_bounds__(256) void sage_gemm_bf(
    const unsigned short* __restrict__ xb,
    const unsigned short* __restrict__ mean_bf,
    const unsigned short* __restrict__ wT,
    const float* __restrict__ bl,
    float* __restrict__ out)    // A': mean fp32 on entry; result on exit
{
    __shared__ unsigned short sW[128 * 256];  // 64 KB
    __shared__ unsigned short sA[32 * 256];   // 16 KB

    const int tid  = threadIdx.x;
    const int lane = tid & 63;
    const int w    = tid >> 6;
    const int l15  = lane & 15;
    const int lg   = lane >> 4;

    #pragma unroll
    for (int i = 0; i < 16; ++i) {
        int c  = tid + i * 256;
        int n  = c >> 5;
        int k8 = c & 31;
        short8 v = ((const short8*)wT)[c];
        *(short8*)&sW[n * 256 + ((k8 ^ (n & 7)) << 3)] = v;
    }

    const int a_r0 = l15;
    const int a_r1 = 16 + l15;
    const int n0 = w * 32 + l15;
    const int n1 = n0 + 16;
    const float bias0 = bl[n0];
    const float bias1 = bl[n1];

    const int nTiles = N_NODES / 32;   // 3125, exact

    for (int tile = blockIdx.x; tile < nTiles; tile += gridDim.x) {
        const int row0 = tile * 32;

        if constexpr (MBF) {
            // 1024 short8 chunks: 32 rows x 32 slots (s<16: mean_bf, s>=16: xb)
            #pragma unroll
            for (int i = 0; i < 4; ++i) {
                int c = tid + i * 256;
                int r = c >> 5;
                int s = c & 31;
                const unsigned short* srcp = (s < 16)
                    ? &mean_bf[(size_t)(row0 + r) * D + s * 8]
                    : &xb[(size_t)(row0 + r) * D + (s - 16) * 8];
                short8 v = *(const short8*)srcp;
                *(short8*)&sA[r * 256 + ((s ^ (r & 7)) << 3)] = v;
            }
        } else {
            // mean half: fp32 from out, convert
            #pragma unroll
            for (int i = 0; i < 4; ++i) {
                int c = tid + i * 256;       // 1024 float4 chunks
                int r = c >> 5;
                int f4 = c & 31;
                float4 v = *(const float4*)&out[(size_t)(row0 + r) * D + f4 * 4];
                short4v b;
                b.x = (short)f2bf(v.x); b.y = (short)f2bf(v.y);
                b.z = (short)f2bf(v.z); b.w = (short)f2bf(v.w);
                int u = f4 >> 1;
                *(short4v*)&sA[r * 256 + ((u ^ (r & 7)) << 3) + (f4 & 1) * 4] = b;
            }
            // x half: bf16 from xb
            #pragma unroll
            for (int i = 0; i < 2; ++i) {
                int c = tid + i * 256;       // 512 short8 chunks
                int r = c >> 4;
                int s = 16 + (c & 15);
                short8 v = *(const short8*)&xb[(size_t)(row0 + r) * D + (c & 15) * 8];
                *(short8*)&sA[r * 256 + ((s ^ (r & 7)) << 3)] = v;
            }
        }
        __syncthreads();

        f32x4 acc00 = {0.f,0.f,0.f,0.f}, acc01 = {0.f,0.f,0.f,0.f};
        f32x4 acc10 = {0.f,0.f,0.f,0.f}, acc11 = {0.f,0.f,0.f,0.f};

        #pragma unroll
        for (int s = 0; s < 8; ++s) {
            int ks = s * 4 + lg;
            short8 a0 = *(const short8*)&sA[a_r0 * 256 + ((ks ^ (a_r0 & 7)) << 3)];
            short8 a1 = *(const short8*)&sA[a_r1 * 256 + ((ks ^ (a_r1 & 7)) << 3)];
            short8 b0 = *(const short8*)&sW[n0 * 256 + ((ks ^ (n0 & 7)) << 3)];
            short8 b1 = *(const short8*)&sW[n1 * 256 + ((ks ^ (n1 & 7)) << 3)];
            acc00 = __builtin_amdgcn_mfma_f32_16x16x32_bf16(a0, b0, acc00, 0, 0, 0);
            acc01 = __builtin_amdgcn_mfma_f32_16x16x32_bf16(a0, b1, acc01, 0, 0, 0);
            acc10 = __builtin_amdgcn_mfma_f32_16x16x32_bf16(a1, b0, acc10, 0, 0, 0);
            acc11 = __builtin_amdgcn_mfma_f32_16x16x32_bf16(a1, b1, acc11, 0, 0, 0);
        }
        __syncthreads();

        #pragma unroll
        for (int reg = 0; reg < 4; ++reg) {
            int r0w = row0 + lg * 4 + reg;
            int r1w = r0w + 16;
            out[(size_t)r0w * D + n0] = acc00[reg] + bias0;
            out[(size_t)r0w * D + n1] = acc01[reg] + bias1;
            out[(size_t)r1w * D + n0] = acc10[reg] + bias0;
            out[(size_t)r1w * D + n1] = acc11[reg] + bias1;
        }
    }
}

// ================= Path B: fp32 gather + R4 MFMA GEMM ======================
__global__ __launch_bounds__(256) void sage_aggregate(
    const float* __restrict__ x,
    const int* __restrict__ ptr,
    const int* __restrict__ sorted_src,
    float* __restrict__ mean)
{
    const int node = blockIdx.x * 4 + (threadIdx.x >> 6);
    if (node >= N_NODES) return;
    const int lane = threadIdx.x & 63;
    const int beg = ptr[node];
    const int end = ptr[node + 1];

    float2 acc0 = make_float2(0.f, 0.f);
    float2 acc1 = make_float2(0.f, 0.f);
    int i = beg;
    for (; i + 1 < end; i += 2) {
        int s0 = sorted_src[i];
        int s1 = sorted_src[i + 1];
        float2 a = *(const float2*)&x[(size_t)s0 * D + lane * 2];
        float2 b = *(const float2*)&x[(size_t)s1 * D + lane * 2];
        acc0.x += a.x; acc0.y += a.y;
        acc1.x += b.x; acc1.y += b.y;
    }
    if (i < end) {
        int s0 = sorted_src[i];
        float2 a = *(const float2*)&x[(size_t)s0 * D + lane * 2];
        acc0.x += a.x; acc0.y += a.y;
    }
    const float sc = 1.0f / fmaxf((float)(end - beg), 1.0f);
    float2 r = make_float2((acc0.x + acc1.x) * sc, (acc0.y + acc1.y) * sc);
    *(float2*)&mean[(size_t)node * D + lane * 2] = r;
}

__global__ __launch_bounds__(256) void sage_gemm_mfma(
    const float* __restrict__ x,
    const unsigned short* __restrict__ wT,
    const float* __restrict__ bl,
    float* __restrict__ out)
{
    __shared__ unsigned short sW[128 * 256];
    __shared__ unsigned short sA[32 * 256];

    const int tid  = threadIdx.x;
    const int lane = tid & 63;
    const int w    = tid >> 6;
    const int l15  = lane & 15;
    const int lg   = lane >> 4;

    #pragma unroll
    for (int i = 0; i < 16; ++i) {
        int c  = tid + i * 256;
        int n  = c >> 5;
        int k8 = c & 31;
        short8 v = ((const short8*)wT)[c];
        *(short8*)&sW[n * 256 + ((k8 ^ (n & 7)) << 3)] = v;
    }

    const int a_r0 = l15;
    const int a_r1 = 16 + l15;
    const int n0 = w * 32 + l15;
    const int n1 = n0 + 16;
    const float bias0 = bl[n0];
    const float bias1 = bl[n1];
    const int nTiles = N_NODES / 32;

    for (int tile = blockIdx.x; tile < nTiles; tile += gridDim.x) {
        const int row0 = tile * 32;
        #pragma unroll
        for (int i = 0; i < 8; ++i) {
            int c    = tid + i * 256;
            int r    = c >> 6;
            int half = (c >> 5) & 1;
            int f4   = c & 31;
            const float* srcp = half ? &x[(size_t)(row0 + r) * D + f4 * 4]
                                     : &out[(size_t)(row0 + r) * D + f4 * 4];
            float4 v = *(const float4*)srcp;
            short4v b;
            b.x = (short)f2bf(v.x); b.y = (short)f2bf(v.y);
            b.z = (short)f2bf(v.z); b.w = (short)f2bf(v.w);
            int k = half * 128 + f4 * 4;
            int u = k >> 3;
            *(short4v*)&sA[r * 256 + ((u ^ (r & 7)) << 3) + (k & 7)] = b;
        }
        __syncthreads();

        f32x4 acc00 = {0.f,0.f,0.f,0.f}, acc01 = {0.f,0.f,0.f,0.f};
        f32x4 acc10 = {0.f,0.f,0.f,0.f}, acc11 = {0.f,0.f,0.f,0.f};

        #pragma unroll
        for (int s = 0; s < 8; ++s) {
            int ks = s * 4 + lg;
            short8 a0 = *(const short8*)&sA[a_r0 * 256 + ((ks ^ (a_r0 & 7)) << 3)];
            short8 a1 = *(const short8*)&sA[a_r1 * 256 + ((ks ^ (a_r1 & 7)) << 3)];
            short8 b0 = *(const short8*)&sW[n0 * 256 + ((ks ^ (n0 & 7)) << 3)];
            short8 b1 = *(const short8*)&sW[n1 * 256 + ((ks ^ (n1 & 7)) << 3)];
            acc00 = __builtin_amdgcn_mfma_f32_16x16x32_bf16(a0, b0, acc00, 0, 0, 0);
            acc01 = __builtin_amdgcn_mfma_f32_16x16x32_bf16(a0, b1, acc01, 0, 0, 0);
            acc10 = __builtin_amdgcn_mfma_f32_16x16x32_bf16(a1, b0, acc10, 0, 0, 0);
            acc11 = __builtin_amdgcn_mfma_f32_16x16x32_bf16(a1, b1, acc11, 0, 0, 0);
        }
        __syncthreads();

        #pragma unroll
        for (int reg = 0; reg < 4; ++reg) {
            int r0w = row0 + lg * 4 + reg;
            int r1w = r0w + 16;
            out[(size_t)r0w * D + n0] = acc00[reg] + bias0;
            out[(size_t)r0w * D + n1] = acc01[reg] + bias1;
            out[(size_t)r1w * D + n0] = acc10[reg] + bias0;
            out[(size_t)r1w * D + n1] = acc11[reg] + bias1;
        }
    }
}

// ================= Path C: scatter fallback ================================
__global__ __launch_bounds__(256) void sage_scatter(
    const float* __restrict__ x, const int* __restrict__ src,
    const int* __restrict__ dst, float* __restrict__ agg, float* __restrict__ deg)
{
    int gid = blockIdx.x * 256 + threadIdx.x;
    int e = gid >> 7;
    if (e >= N_EDGES) return;
    int d = gid & 127;
    atomicAdd(&agg[(size_t)dst[e] * D + d], x[(size_t)src[e] * D + d]);
    if (d == 0) atomicAdd(&deg[dst[e]], 1.0f);
}

__global__ __launch_bounds__(256) void apply_mean(
    float* __restrict__ agg, const float* __restrict__ deg)
{
    int gid = blockIdx.x * 256 + threadIdx.x;
    int row = gid >> 5;
    if (row >= N_NODES) return;
    float sc = 1.0f / fmaxf(deg[row], 1.0f);
    float4 v = ((float4*)agg)[gid];
    v.x *= sc; v.y *= sc; v.z *= sc; v.w *= sc;
    ((float4*)agg)[gid] = v;
}

__device__ __forceinline__ void accum_tile(
    float acc[4][4], const float (*sWf)[D], const float (*srow)[D], int h, int j4)
{
    #pragma unroll 2
    for (int k = 0; k < D; k += 4) {
        float4 w0 = *(const float4*)&sWf[k + 0][j4];
        float4 w1 = *(const float4*)&sWf[k + 1][j4];
        float4 w2 = *(const float4*)&sWf[k + 2][j4];
        float4 w3 = *(const float4*)&sWf[k + 3][j4];
        #pragma unroll
        for (int r = 0; r < 4; ++r) {
            float4 a = *(const float4*)&srow[h + r * 8][k];
            acc[r][0] = fmaf(a.x, w0.x, fmaf(a.y, w1.x, fmaf(a.z, w2.x, fmaf(a.w, w3.x, acc[r][0]))));
            acc[r][1] = fmaf(a.x, w0.y, fmaf(a.y, w1.y, fmaf(a.z, w2.y, fmaf(a.w, w3.y, acc[r][1]))));
            acc[r][2] = fmaf(a.x, w0.z, fmaf(a.y, w1.z, fmaf(a.z, w2.z, fmaf(a.w, w3.z, acc[r][2]))));
            acc[r][3] = fmaf(a.x, w0.w, fmaf(a.y, w1.w, fmaf(a.z, w2.w, fmaf(a.w, w3.w, acc[r][3]))));
        }
    }
}

__global__ __launch_bounds__(256) void sage_gemm_f32(
    const float* __restrict__ x, const float* __restrict__ Wl,
    const float* __restrict__ bl, const float* __restrict__ Wr,
    float* __restrict__ out)
{
    __shared__ float sWf[D][D];
    __shared__ float srow[32][D];
    const int tid = threadIdx.x;
    const int j4 = (tid & 31) * 4;
    const int h  = tid >> 5;
    const int nTiles = (N_NODES + 31) / 32;
    const float4 bias = *(const float4*)(bl + j4);

    for (int tile = blockIdx.x; tile < nTiles; tile += gridDim.x) {
        const int row0 = tile * 32;
        float acc[4][4];
        #pragma unroll
        for (int r = 0; r < 4; ++r)
            #pragma unroll
            for (int c = 0; c < 4; ++c) acc[r][c] = 0.0f;

        __syncthreads();
        #pragma unroll
        for (int i = 0; i < 16; ++i)
            ((float4*)sWf)[tid + i * 256] = ((const float4*)Wl)[tid + i * 256];
        #pragma unroll
        for (int i = 0; i < 4; ++i) {
            int idx = tid + i * 256, r = idx >> 5, c = idx & 31, row = row0 + r;
            float4 v = make_float4(0.f,0.f,0.f,0.f);
            if (row < N_NODES) v = ((const float4*)out)[(size_t)row * 32 + c];
            ((float4*)srow)[idx] = v;
        }
        __syncthreads();
        accum_tile(acc, sWf, srow, h, j4);

        __syncthreads();
        #pragma unroll
        for (int i = 0; i < 16; ++i)
            ((float4*)sWf)[tid + i * 256] = ((const float4*)Wr)[tid + i * 256];
        #pragma unroll
        for (int i = 0; i < 4; ++i) {
            int idx = tid + i * 256, r = idx >> 5, c = idx & 31, row = row0 + r;
            float4 v = make_float4(0.f,0.f,0.f,0.f);
            if (row < N_NODES) v = ((const float4*)x)[(size_t)row * 32 + c];
            ((float4*)srow)[idx] = v;
        }
        __syncthreads();
        accum_tile(acc, sWf, srow, h, j4);

        #pragma unroll
        for (int r = 0; r < 4; ++r) {
            int row = row0 + h + r * 8;
            if (row < N_NODES) {
                float4 v = make_float4(acc[r][0] + bias.x, acc[r][1] + bias.y,
                                       acc[r][2] + bias.z, acc[r][3] + bias.w);
                *(float4*)(out + (size_t)row * D + j4) = v;
            }
        }
    }
}

extern "C" void kernel_launch(void* const* d_in, const int* in_sizes, int n_in,
                              void* d_out, int out_size, void* d_ws, size_t ws_size,
                              hipStream_t stream) {
    const float* x   = (const float*)d_in[0];
    const int*   ei  = (const int*)d_in[1];
    const float* Wl  = (const float*)d_in[2];
    const float* bl  = (const float*)d_in[3];
    const float* Wr  = (const float*)d_in[4];
    float* out = (float*)d_out;

    const int* src = ei;
    const int* dst = ei + N_EDGES;

    int* cnt    = (int*)d_ws;                    // N
    int* ptr    = cnt + N_NODES;                 // N+1
    int* cursor = ptr + N_NODES + 1;             // N  (reused as wT after csr_fill)
    int* bsums  = cursor + N_NODES;              // 128
    int* sorted = bsums + 128;                   // E
    unsigned short* xb      = (unsigned short*)(sorted + N_EDGES);   // N*D bf16
    unsigned short* mean_bf = xb + (size_t)N_NODES * D;              // N*D bf16

    size_t base_ints = (size_t)(3 * N_NODES + 1 + 128 + N_EDGES);
    size_t need_B  = base_ints * sizeof(int);
    size_t need_A2 = need_B + (size_t)N_NODES * D * 2;       // + xb
    size_t need_A  = need_A2 + (size_t)N_NODES * D * 2;      // + mean_bf

    if (ws_size >= need_B) {
        // ---- CSR build (shared by A/A'/B) ----
        hipMemsetAsync(cnt, 0, (size_t)N_NODES * sizeof(int), stream);
        csr_hist<<<(N_EDGES + 255) / 256, 256, 0, stream>>>(dst, cnt);
        scan_blocks<<<N_SCAN_BLOCKS, 256, 0, stream>>>(cnt, ptr, bsums);
        scan_bsums<<<1, 128, 0, stream>>>(bsums);
        add_offsets<<<(N_NODES + 255) / 256, 256, 0, stream>>>(ptr, cursor, bsums);
        csr_fill<<<(N_EDGES + 255) / 256, 256, 0, stream>>>(src, dst, cursor, sorted);

        unsigned short* wT = (unsigned short*)cursor;   // cursor dead after fill
        wt_build<<<(128 * 256 + 255) / 256, 256, 0, stream>>>(Wl, Wr, wT);

        if (ws_size >= need_A) {
            x2bf<<<(N_NODES * D / 8 + 255) / 256, 256, 0, stream>>>(x, xb);
            sage_aggregate_bf<true><<<(N_NODES + 3) / 4, 256, 0, stream>>>(
                xb, ptr, sorted, mean_bf, nullptr);
            sage_gemm_bf<true><<<512, 256, 0, stream>>>(xb, mean_bf, wT, bl, out);
        } else if (ws_size >= need_A2) {
            x2bf<<<(N_NODES * D / 8 + 255) / 256, 256, 0, stream>>>(x, xb);
            sage_aggregate_bf<false><<<(N_NODES + 3) / 4, 256, 0, stream>>>(
                xb, ptr, sorted, nullptr, out);
            sage_gemm_bf<false><<<512, 256, 0, stream>>>(xb, nullptr, wT, bl, out);
        } else {
            sage_aggregate<<<(N_NODES + 3) / 4, 256, 0, stream>>>(x, ptr, sorted, out);
            sage_gemm_mfma<<<512, 256, 0, stream>>>(x, wT, bl, out);
        }
    } else {
        float* deg = (float*)d_ws;
        hipMemsetAsync(out, 0, (size_t)N_NODES * D * sizeof(float), stream);
        hipMemsetAsync(deg, 0, (size_t)N_NODES * sizeof(float), stream);
        long long total = (long long)N_EDGES * 128;
        sage_scatter<<<(int)((total + 255) / 256), 256, 0, stream>>>(x, src, dst, out, deg);
        apply_mean<<<(N_NODES * 32 + 255) / 256, 256, 0, stream>>>(out, deg);
        sage_gemm_f32<<<512, 256, 0, stream>>>(x, Wl, bl, Wr, out);
    }
}

// Round 6
// 144.896 us; speedup vs baseline: 36.0860x; 1.0645x over previous
//
#include <hip/hip_runtime.h>

// SAGEConv: out = (mean_{j in N(i)} x_j) @ W_l + b_l + x_i @ W_r
// Inputs: x [N,128] f32, edge_index [2,E] int32, W_l [128,128] f32, b_l [128] f32, W_r [128,128] f32
// Output: [N,128] f32
//
// Path A: CSR build -> prep (x->bf16 + W^T bf16) -> gather-mean (16 lanes/node,
//         16B loads, 4-way ILP) -> bf16 MFMA dual-GEMM (K=256).
// Fallbacks: A' (fp32 mean in d_out), B (fp32 gather + convert-in-GEMM), C (atomic scatter).

constexpr int N_NODES = 100000;
constexpr int N_EDGES = 625000;
constexpr int D = 128;
constexpr int SCAN_CHUNK = 1024;
constexpr int N_SCAN_BLOCKS = (N_NODES + SCAN_CHUNK - 1) / SCAN_CHUNK;  // 98

typedef __attribute__((ext_vector_type(8))) short short8;
typedef __attribute__((ext_vector_type(4))) short short4v;
typedef __attribute__((ext_vector_type(4))) float f32x4;

__device__ __forceinline__ unsigned short f2bf(float f) {
    union { float f; unsigned int u; } c; c.f = f;
    unsigned int u = c.u + 0x7fffu + ((c.u >> 16) & 1u);   // RNE
    return (unsigned short)(u >> 16);
}
__device__ __forceinline__ float bflo(unsigned int v) {
    union { unsigned int u; float f; } c; c.u = v << 16; return c.f;
}
__device__ __forceinline__ float bfhi(unsigned int v) {
    union { unsigned int u; float f; } c; c.u = v & 0xffff0000u; return c.f;
}

// ================= CSR build =================
__global__ __launch_bounds__(256) void csr_hist(
    const int* __restrict__ dst, int* __restrict__ cnt)
{
    int e = blockIdx.x * 256 + threadIdx.x;
    if (e < N_EDGES) atomicAdd(&cnt[dst[e]], 1);
}

__global__ __launch_bounds__(256) void scan_blocks(
    const int* __restrict__ cnt, int* __restrict__ ptr, int* __restrict__ bsums)
{
    __shared__ int sh[256];
    const int t = threadIdx.x;
    const int base = blockIdx.x * SCAN_CHUNK + t * 4;
    int v0 = (base + 0 < N_NODES) ? cnt[base + 0] : 0;
    int v1 = (base + 1 < N_NODES) ? cnt[base + 1] : 0;
    int v2 = (base + 2 < N_NODES) ? cnt[base + 2] : 0;
    int v3 = (base + 3 < N_NODES) ? cnt[base + 3] : 0;
    const int tsum = v0 + v1 + v2 + v3;
    sh[t] = tsum;
    __syncthreads();
    #pragma unroll
    for (int off = 1; off < 256; off <<= 1) {
        int val = (t >= off) ? sh[t - off] : 0;
        __syncthreads();
        sh[t] += val;
        __syncthreads();
    }
    const int texcl = sh[t] - tsum;
    if (t == 255) bsums[blockIdx.x] = sh[255];
    int e0 = texcl, e1 = e0 + v0, e2 = e1 + v1, e3 = e2 + v2;
    if (base + 0 < N_NODES) ptr[base + 0] = e0;
    if (base + 1 < N_NODES) ptr[base + 1] = e1;
    if (base + 2 < N_NODES) ptr[base + 2] = e2;
    if (base + 3 < N_NODES) ptr[base + 3] = e3;
}

// add_offsets with fused bsums-prefix (each block reduces bsums[0..blockIdx) itself)
__global__ __launch_bounds__(256) void add_offsets_fused(
    int* __restrict__ ptr, int* __restrict__ cursor, const int* __restrict__ bsums)
{
    __shared__ int sh[256];
    const int t = threadIdx.x;
    int v = (t < blockIdx.x) ? bsums[t] : 0;   // blockIdx.x <= 97 < 256
    sh[t] = v;
    __syncthreads();
    #pragma unroll
    for (int off = 128; off > 0; off >>= 1) {
        if (t < off) sh[t] += sh[t + off];
        __syncthreads();
    }
    const int soff = sh[0];
    const int base = blockIdx.x * SCAN_CHUNK + t * 4;
    #pragma unroll
    for (int j = 0; j < 4; ++j) {
        int i = base + j;
        if (i < N_NODES) {
            int p = ptr[i] + soff;
            ptr[i] = p;
            cursor[i] = p;
        }
    }
    if (blockIdx.x == 0 && t == 0) ptr[N_NODES] = N_EDGES;
}

__global__ __launch_bounds__(256) void csr_fill(
    const int* __restrict__ src, const int* __restrict__ dst,
    int* __restrict__ cursor, int* __restrict__ sorted_src)
{
    int e = blockIdx.x * 256 + threadIdx.x;
    if (e < N_EDGES) {
        int t = dst[e];
        int pos = atomicAdd(&cursor[t], 1);
        sorted_src[pos] = src[e];
    }
}

// ================= prep: x -> bf16  +  W^T bf16 =================
__global__ __launch_bounds__(256) void prep_bf(
    const float* __restrict__ x, const float* __restrict__ Wl,
    const float* __restrict__ Wr,
    unsigned short* __restrict__ xb, unsigned short* __restrict__ wT)
{
    const int XC = N_NODES * D / 8;            // 1,600,000 short8 chunks
    int c = blockIdx.x * 256 + threadIdx.x;
    if (c < XC) {
        const float4* xp = (const float4*)x;
        float4 a = xp[(size_t)c * 2];
        float4 b = xp[(size_t)c * 2 + 1];
        short8 v;
        v[0] = (short)f2bf(a.x); v[1] = (short)f2bf(a.y);
        v[2] = (short)f2bf(a.z); v[3] = (short)f2bf(a.w);
        v[4] = (short)f2bf(b.x); v[5] = (short)f2bf(b.y);
        v[6] = (short)f2bf(b.z); v[7] = (short)f2bf(b.w);
        ((short8*)xb)[c] = v;
    } else if (c < XC + 4096) {                // 128*256/8 wT chunks
        int idx = c - XC;
        int n  = idx >> 5;
        int k0 = (idx & 31) * 8;
        short8 v;
        #pragma unroll
        for (int j = 0; j < 8; ++j) {
            int k = k0 + j;
            float f = (k < 128) ? Wl[k * 128 + n] : Wr[(k - 128) * 128 + n];
            v[j] = (short)f2bf(f);
        }
        *(short8*)&wT[n * 256 + k0] = v;
    }
}

// standalone W^T build (fallback B, aliases cursor)
__global__ __launch_bounds__(256) void wt_build(
    const float* __restrict__ Wl, const float* __restrict__ Wr,
    unsigned short* __restrict__ wT)
{
    int idx = blockIdx.x * 256 + threadIdx.x;
    if (idx >= 128 * 256) return;
    int n = idx >> 8;
    int k = idx & 255;
    float v = (k < 128) ? Wl[k * 128 + n] : Wr[(k - 128) * 128 + n];
    wT[n * 256 + k] = f2bf(v);
}

// ====== gather-mean: 16 lanes/node (4 nodes per wave), 16B loads, 4-ILP ======
template<bool MBF>
__global__ __launch_bounds__(256) void sage_aggregate_bf(
    const unsigned short* __restrict__ xb,
    const int* __restrict__ ptr,
    const int* __restrict__ sorted_src,
    unsigned short* __restrict__ mean_bf,
    float* __restrict__ mean_f32)
{
    const int node = blockIdx.x * 16 + (threadIdx.x >> 4);
    if (node >= N_NODES) return;
    const int l = threadIdx.x & 15;
    const int beg = ptr[node];
    const int end = ptr[node + 1];
    const size_t off = (size_t)l * 8;          // 8 bf16 = 16B per lane

    float a0=0,a1=0,a2=0,a3=0,a4=0,a5=0,a6=0,a7=0;
    float b0=0,b1=0,b2=0,b3=0,b4=0,b5=0,b6=0,b7=0;
    float c0=0,c1=0,c2=0,c3=0,c4=0,c5=0,c6=0,c7=0;
    float d0=0,d1=0,d2=0,d3=0,d4=0,d5=0,d6=0,d7=0;

    int i = beg;
    for (; i + 3 < end; i += 4) {
        int s0 = sorted_src[i],     s1 = sorted_src[i + 1];
        int s2 = sorted_src[i + 2], s3 = sorted_src[i + 3];
        uint4 v0 = *(const uint4*)&xb[(size_t)s0 * D + off];
        uint4 v1 = *(const uint4*)&xb[(size_t)s1 * D + off];
        uint4 v2 = *(const uint4*)&xb[(size_t)s2 * D + off];
        uint4 v3 = *(const uint4*)&xb[(size_t)s3 * D + off];
        a0+=bflo(v0.x); a1+=bfhi(v0.x); a2+=bflo(v0.y); a3+=bfhi(v0.y);
        a4+=bflo(v0.z); a5+=bfhi(v0.z); a6+=bflo(v0.w); a7+=bfhi(v0.w);
        b0+=bflo(v1.x); b1+=bfhi(v1.x); b2+=bflo(v1.y); b3+=bfhi(v1.y);
        b4+=bflo(v1.z); b5+=bfhi(v1.z); b6+=bflo(v1.w); b7+=bfhi(v1.w);
        c0+=bflo(v2.x); c1+=bfhi(v2.x); c2+=bflo(v2.y); c3+=bfhi(v2.y);
        c4+=bflo(v2.z); c5+=bfhi(v2.z); c6+=bflo(v2.w); c7+=bfhi(v2.w);
        d0+=bflo(v3.x); d1+=bfhi(v3.x); d2+=bflo(v3.y); d3+=bfhi(v3.y);
        d4+=bflo(v3.z); d5+=bfhi(v3.z); d6+=bflo(v3.w); d7+=bfhi(v3.w);
    }
    for (; i < end; ++i) {
        int s0 = sorted_src[i];
        uint4 v0 = *(const uint4*)&xb[(size_t)s0 * D + off];
        a0+=bflo(v0.x); a1+=bfhi(v0.x); a2+=bflo(v0.y); a3+=bfhi(v0.y);
        a4+=bflo(v0.z); a5+=bfhi(v0.z); a6+=bflo(v0.w); a7+=bfhi(v0.w);
    }
    const float sc = 1.0f / fmaxf((float)(end - beg), 1.0f);
    float r0 = ((a0+b0)+(c0+d0))*sc, r1 = ((a1+b1)+(c1+d1))*sc;
    float r2 = ((a2+b2)+(c2+d2))*sc, r3 = ((a3+b3)+(c3+d3))*sc;
    float r4 = ((a4+b4)+(c4+d4))*sc, r5 = ((a5+b5)+(c5+d5))*sc;
    float r6 = ((a6+b6)+(c6+d6))*sc, r7 = ((a7+b7)+(c7+d7))*sc;

    if constexpr (MBF) {
        uint4 o;
        o.x = (unsigned)f2bf(r0) | ((unsigned)f2bf(r1) << 16);
        o.y = (unsigned)f2bf(r2) | ((unsigned)f2bf(r3) << 16);
        o.z = (unsigned)f2bf(r4) | ((unsigned)f2bf(r5) << 16);
        o.w = (unsigned)f2bf(r6) | ((unsigned)f2bf(r7) << 16);
        *(uint4*)&mean_bf[(size_t)node * D + off] = o;
    } else {
        *(float4*)&mean_f32[(size_t)node * D + off] = make_float4(r0, r1, r2, r3);
        *(float4*)&mean_f32[(size_t)node * D + off + 4] = make_float4(r4, r5, r6, r7);
    }
}

// ================= bf16 MFMA GEMM (Path A / A') ============================
template<bool MBF>
__global__ __launch_bounds__(256) void sage_gemm_bf(
    const unsigned short* __restrict__ xb,
    const unsigned short* __restrict__ mean_bf,
    const unsigned short* __restrict__ wT,
    const float* __restrict__ bl,
    float* __restrict__ out)
{
    __shared__ unsigned short sW[128 * 256];  // 64 KB
    __shared__ unsigned short sA[32 * 256];   // 16 KB

    const int tid  = threadIdx.x;
    const int lane = tid & 63;
    const int w    = tid >> 6;
    const int l15  = lane & 15;
    const int lg   = lane >> 4;

    #pragma unroll
    for (int i = 0; i < 16; ++i) {
        int c  = tid + i * 256;
        int n  = c >> 5;
        int k8 = c & 31;
        short8 v = ((const short8*)wT)[c];
        *(short8*)&sW[n * 256 + ((k8 ^ (n & 7)) << 3)] = v;
    }

    const int a_r0 = l15;
    const int a_r1 = 16 + l15;
    const int n0 = w * 32 + l15;
    const int n1 = n0 + 16;
    const float bias0 = bl[n0];
    const float bias1 = bl[n1];

    const int nTiles = N_NODES / 32;   // 3125, exact

    for (int tile = blockIdx.x; tile < nTiles; tile += gridDim.x) {
        const int row0 = tile * 32;

        if constexpr (MBF) {
            #pragma unroll
            for (int i = 0; i < 4; ++i) {
                int c = tid + i * 256;
                int r = c >> 5;
                int s = c & 31;
                const unsigned short* srcp = (s < 16)
                    ? &mean_bf[(size_t)(row0 + r) * D + s * 8]
                    : &xb[(size_t)(row0 + r) * D + (s - 16) * 8];
                short8 v = *(const short8*)srcp;
                *(short8*)&sA[r * 256 + ((s ^ (r & 7)) << 3)] = v;
            }
        } else {
            #pragma unroll
            for (int i = 0; i < 4; ++i) {
                int c = tid + i * 256;
                int r = c >> 5;
                int f4 = c & 31;
                float4 v = *(const float4*)&out[(size_t)(row0 + r) * D + f4 * 4];
                short4v b;
                b.x = (short)f2bf(v.x); b.y = (short)f2bf(v.y);
                b.z = (short)f2bf(v.z); b.w = (short)f2bf(v.w);
                int u = f4 >> 1;
                *(short4v*)&sA[r * 256 + ((u ^ (r & 7)) << 3) + (f4 & 1) * 4] = b;
            }
            #pragma unroll
            for (int i = 0; i < 2; ++i) {
                int c = tid + i * 256;
                int r = c >> 4;
                int s = 16 + (c & 15);
                short8 v = *(const short8*)&xb[(size_t)(row0 + r) * D + (c & 15) * 8];
                *(short8*)&sA[r * 256 + ((s ^ (r & 7)) << 3)] = v;
            }
        }
        __syncthreads();

        f32x4 acc00 = {0.f,0.f,0.f,0.f}, acc01 = {0.f,0.f,0.f,0.f};
        f32x4 acc10 = {0.f,0.f,0.f,0.f}, acc11 = {0.f,0.f,0.f,0.f};

        #pragma unroll
        for (int s = 0; s < 8; ++s) {
            int ks = s * 4 + lg;
            short8 a0 = *(const short8*)&sA[a_r0 * 256 + ((ks ^ (a_r0 & 7)) << 3)];
            short8 a1 = *(const short8*)&sA[a_r1 * 256 + ((ks ^ (a_r1 & 7)) << 3)];
            short8 b0 = *(const short8*)&sW[n0 * 256 + ((ks ^ (n0 & 7)) << 3)];
            short8 b1 = *(const short8*)&sW[n1 * 256 + ((ks ^ (n1 & 7)) << 3)];
            acc00 = __builtin_amdgcn_mfma_f32_16x16x32_bf16(a0, b0, acc00, 0, 0, 0);
            acc01 = __builtin_amdgcn_mfma_f32_16x16x32_bf16(a0, b1, acc01, 0, 0, 0);
            acc10 = __builtin_amdgcn_mfma_f32_16x16x32_bf16(a1, b0, acc10, 0, 0, 0);
            acc11 = __builtin_amdgcn_mfma_f32_16x16x32_bf16(a1, b1, acc11, 0, 0, 0);
        }
        __syncthreads();

        #pragma unroll
        for (int reg = 0; reg < 4; ++reg) {
            int r0w = row0 + lg * 4 + reg;
            int r1w = r0w + 16;
            out[(size_t)r0w * D + n0] = acc00[reg] + bias0;
            out[(size_t)r0w * D + n1] = acc01[reg] + bias1;
            out[(size_t)r1w * D + n0] = acc10[reg] + bias0;
            out[(size_t)r1w * D + n1] = acc11[reg] + bias1;
        }
    }
}

// ================= Path B: fp32 gather + convert-in-GEMM ===================
__global__ __launch_bounds__(256) void sage_aggregate(
    const float* __restrict__ x,
    const int* __restrict__ ptr,
    const int* __restrict__ sorted_src,
    float* __restrict__ mean)
{
    const int node = blockIdx.x * 4 + (threadIdx.x >> 6);
    if (node >= N_NODES) return;
    const int lane = threadIdx.x & 63;
    const int beg = ptr[node];
    const int end = ptr[node + 1];

    float2 acc0 = make_float2(0.f, 0.f);
    float2 acc1 = make_float2(0.f, 0.f);
    int i = beg;
    for (; i + 1 < end; i += 2) {
        int s0 = sorted_src[i];
        int s1 = sorted_src[i + 1];
        float2 a = *(const float2*)&x[(size_t)s0 * D + lane * 2];
        float2 b = *(const float2*)&x[(size_t)s1 * D + lane * 2];
        acc0.x += a.x; acc0.y += a.y;
        acc1.x += b.x; acc1.y += b.y;
    }
    if (i < end) {
        int s0 = sorted_src[i];
        float2 a = *(const float2*)&x[(size_t)s0 * D + lane * 2];
        acc0.x += a.x; acc0.y += a.y;
    }
    const float sc = 1.0f / fmaxf((float)(end - beg), 1.0f);
    float2 r = make_float2((acc0.x + acc1.x) * sc, (acc0.y + acc1.y) * sc);
    *(float2*)&mean[(size_t)node * D + lane * 2] = r;
}

__global__ __launch_bounds__(256) void sage_gemm_mfma(
    const float* __restrict__ x,
    const unsigned short* __restrict__ wT,
    const float* __restrict__ bl,
    float* __restrict__ out)
{
    __shared__ unsigned short sW[128 * 256];
    __shared__ unsigned short sA[32 * 256];

    const int tid  = threadIdx.x;
    const int lane = tid & 63;
    const int w    = tid >> 6;
    const int l15  = lane & 15;
    const int lg   = lane >> 4;

    #pragma unroll
    for (int i = 0; i < 16; ++i) {
        int c  = tid + i * 256;
        int n  = c >> 5;
        int k8 = c & 31;
        short8 v = ((const short8*)wT)[c];
        *(short8*)&sW[n * 256 + ((k8 ^ (n & 7)) << 3)] = v;
    }

    const int a_r0 = l15;
    const int a_r1 = 16 + l15;
    const int n0 = w * 32 + l15;
    const int n1 = n0 + 16;
    const float bias0 = bl[n0];
    const float bias1 = bl[n1];
    const int nTiles = N_NODES / 32;

    for (int tile = blockIdx.x; tile < nTiles; tile += gridDim.x) {
        const int row0 = tile * 32;
        #pragma unroll
        for (int i = 0; i < 8; ++i) {
            int c    = tid + i * 256;
            int r    = c >> 6;
            int half = (c >> 5) & 1;
            int f4   = c & 31;
            const float* srcp = half ? &x[(size_t)(row0 + r) * D + f4 * 4]
                                     : &out[(size_t)(row0 + r) * D + f4 * 4];
            float4 v = *(const float4*)srcp;
            short4v b;
            b.x = (short)f2bf(v.x); b.y = (short)f2bf(v.y);
            b.z = (short)f2bf(v.z); b.w = (short)f2bf(v.w);
            int k = half * 128 + f4 * 4;
            int u = k >> 3;
            *(short4v*)&sA[r * 256 + ((u ^ (r & 7)) << 3) + (k & 7)] = b;
        }
        __syncthreads();

        f32x4 acc00 = {0.f,0.f,0.f,0.f}, acc01 = {0.f,0.f,0.f,0.f};
        f32x4 acc10 = {0.f,0.f,0.f,0.f}, acc11 = {0.f,0.f,0.f,0.f};

        #pragma unroll
        for (int s = 0; s < 8; ++s) {
            int ks = s * 4 + lg;
            short8 a0 = *(const short8*)&sA[a_r0 * 256 + ((ks ^ (a_r0 & 7)) << 3)];
            short8 a1 = *(const short8*)&sA[a_r1 * 256 + ((ks ^ (a_r1 & 7)) << 3)];
            short8 b0 = *(const short8*)&sW[n0 * 256 + ((ks ^ (n0 & 7)) << 3)];
            short8 b1 = *(const short8*)&sW[n1 * 256 + ((ks ^ (n1 & 7)) << 3)];
            acc00 = __builtin_amdgcn_mfma_f32_16x16x32_bf16(a0, b0, acc00, 0, 0, 0);
            acc01 = __builtin_amdgcn_mfma_f32_16x16x32_bf16(a0, b1, acc01, 0, 0, 0);
            acc10 = __builtin_amdgcn_mfma_f32_16x16x32_bf16(a1, b0, acc10, 0, 0, 0);
            acc11 = __builtin_amdgcn_mfma_f32_16x16x32_bf16(a1, b1, acc11, 0, 0, 0);
        }
        __syncthreads();

        #pragma unroll
        for (int reg = 0; reg < 4; ++reg) {
            int r0w = row0 + lg * 4 + reg;
            int r1w = r0w + 16;
            out[(size_t)r0w * D + n0] = acc00[reg] + bias0;
            out[(size_t)r0w * D + n1] = acc01[reg] + bias1;
            out[(size_t)r1w * D + n0] = acc10[reg] + bias0;
            out[(size_t)r1w * D + n1] = acc11[reg] + bias1;
        }
    }
}

// ================= Path C: scatter fallback ================================
__global__ __launch_bounds__(256) void sage_scatter(
    const float* __restrict__ x, const int* __restrict__ src,
    const int* __restrict__ dst, float* __restrict__ agg, float* __restrict__ deg)
{
    int gid = blockIdx.x * 256 + threadIdx.x;
    int e = gid >> 7;
    if (e >= N_EDGES) return;
    int d = gid & 127;
    atomicAdd(&agg[(size_t)dst[e] * D + d], x[(size_t)src[e] * D + d]);
    if (d == 0) atomicAdd(&deg[dst[e]], 1.0f);
}

__global__ __launch_bounds__(256) void apply_mean(
    float* __restrict__ agg, const float* __restrict__ deg)
{
    int gid = blockIdx.x * 256 + threadIdx.x;
    int row = gid >> 5;
    if (row >= N_NODES) return;
    float sc = 1.0f / fmaxf(deg[row], 1.0f);
    float4 v = ((float4*)agg)[gid];
    v.x *= sc; v.y *= sc; v.z *= sc; v.w *= sc;
    ((float4*)agg)[gid] = v;
}

__device__ __forceinline__ void accum_tile(
    float acc[4][4], const float (*sWf)[D], const float (*srow)[D], int h, int j4)
{
    #pragma unroll 2
    for (int k = 0; k < D; k += 4) {
        float4 w0 = *(const float4*)&sWf[k + 0][j4];
        float4 w1 = *(const float4*)&sWf[k + 1][j4];
        float4 w2 = *(const float4*)&sWf[k + 2][j4];
        float4 w3 = *(const float4*)&sWf[k + 3][j4];
        #pragma unroll
        for (int r = 0; r < 4; ++r) {
            float4 a = *(const float4*)&srow[h + r * 8][k];
            acc[r][0] = fmaf(a.x, w0.x, fmaf(a.y, w1.x, fmaf(a.z, w2.x, fmaf(a.w, w3.x, acc[r][0]))));
            acc[r][1] = fmaf(a.x, w0.y, fmaf(a.y, w1.y, fmaf(a.z, w2.y, fmaf(a.w, w3.y, acc[r][1]))));
            acc[r][2] = fmaf(a.x, w0.z, fmaf(a.y, w1.z, fmaf(a.z, w2.z, fmaf(a.w, w3.z, acc[r][2]))));
            acc[r][3] = fmaf(a.x, w0.w, fmaf(a.y, w1.w, fmaf(a.z, w2.w, fmaf(a.w, w3.w, acc[r][3]))));
        }
    }
}

__global__ __launch_bounds__(256) void sage_gemm_f32(
    const float* __restrict__ x, const float* __restrict__ Wl,
    const float* __restrict__ bl, const float* __restrict__ Wr,
    float* __restrict__ out)
{
    __shared__ float sWf[D][D];
    __shared__ float srow[32][D];
    const int tid = threadIdx.x;
    const int j4 = (tid & 31) * 4;
    const int h  = tid >> 5;
    const int nTiles = (N_NODES + 31) / 32;
    const float4 bias = *(const float4*)(bl + j4);

    for (int tile = blockIdx.x; tile < nTiles; tile += gridDim.x) {
        const int row0 = tile * 32;
        float acc[4][4];
        #pragma unroll
        for (int r = 0; r < 4; ++r)
            #pragma unroll
            for (int c = 0; c < 4; ++c) acc[r][c] = 0.0f;

        __syncthreads();
        #pragma unroll
        for (int i = 0; i < 16; ++i)
            ((float4*)sWf)[tid + i * 256] = ((const float4*)Wl)[tid + i * 256];
        #pragma unroll
        for (int i = 0; i < 4; ++i) {
            int idx = tid + i * 256, r = idx >> 5, c = idx & 31, row = row0 + r;
            float4 v = make_float4(0.f,0.f,0.f,0.f);
            if (row < N_NODES) v = ((const float4*)out)[(size_t)row * 32 + c];
            ((float4*)srow)[idx] = v;
        }
        __syncthreads();
        accum_tile(acc, sWf, srow, h, j4);

        __syncthreads();
        #pragma unroll
        for (int i = 0; i < 16; ++i)
            ((float4*)sWf)[tid + i * 256] = ((const float4*)Wr)[tid + i * 256];
        #pragma unroll
        for (int i = 0; i < 4; ++i) {
            int idx = tid + i * 256, r = idx >> 5, c = idx & 31, row = row0 + r;
            float4 v = make_float4(0.f,0.f,0.f,0.f);
            if (row < N_NODES) v = ((const float4*)x)[(size_t)row * 32 + c];
            ((float4*)srow)[idx] = v;
        }
        __syncthreads();
        accum_tile(acc, sWf, srow, h, j4);

        #pragma unroll
        for (int r = 0; r < 4; ++r) {
            int row = row0 + h + r * 8;
            if (row < N_NODES) {
                float4 v = make_float4(acc[r][0] + bias.x, acc[r][1] + bias.y,
                                       acc[r][2] + bias.z, acc[r][3] + bias.w);
                *(float4*)(out + (size_t)row * D + j4) = v;
            }
        }
    }
}

extern "C" void kernel_launch(void* const* d_in, const int* in_sizes, int n_in,
                              void* d_out, int out_size, void* d_ws, size_t ws_size,
                              hipStream_t stream) {
    const float* x   = (const float*)d_in[0];
    const int*   ei  = (const int*)d_in[1];
    const float* Wl  = (const float*)d_in[2];
    const float* bl  = (const float*)d_in[3];
    const float* Wr  = (const float*)d_in[4];
    float* out = (float*)d_out;

    const int* src = ei;
    const int* dst = ei + N_EDGES;

    int* cnt    = (int*)d_ws;                    // N
    int* ptr    = cnt + N_NODES;                 // N+1
    int* cursor = ptr + N_NODES + 1;             // N
    int* bsums  = cursor + N_NODES;              // 128
    int* sorted = bsums + 128;                   // E
    unsigned short* wT      = (unsigned short*)(sorted + N_EDGES);   // 128*256 bf16
    unsigned short* xb      = wT + 128 * 256;                        // N*D bf16
    unsigned short* mean_bf = xb + (size_t)N_NODES * D;              // N*D bf16

    size_t base_ints = (size_t)(3 * N_NODES + 1 + 128 + N_EDGES);
    size_t need_B  = base_ints * sizeof(int);
    size_t need_A2 = need_B + 128 * 256 * 2 + (size_t)N_NODES * D * 2;  // + wT + xb
    size_t need_A  = need_A2 + (size_t)N_NODES * D * 2;                 // + mean_bf

    if (ws_size >= need_B) {
        // ---- CSR build (shared by A/A'/B) ----
        hipMemsetAsync(cnt, 0, (size_t)N_NODES * sizeof(int), stream);
        csr_hist<<<(N_EDGES + 255) / 256, 256, 0, stream>>>(dst, cnt);
        scan_blocks<<<N_SCAN_BLOCKS, 256, 0, stream>>>(cnt, ptr, bsums);
        add_offsets_fused<<<N_SCAN_BLOCKS, 256, 0, stream>>>(ptr, cursor, bsums);
        csr_fill<<<(N_EDGES + 255) / 256, 256, 0, stream>>>(src, dst, cursor, sorted);

        if (ws_size >= need_A) {
            prep_bf<<<(N_NODES * D / 8 + 4096 + 255) / 256, 256, 0, stream>>>(x, Wl, Wr, xb, wT);
            sage_aggregate_bf<true><<<(N_NODES + 15) / 16, 256, 0, stream>>>(
                xb, ptr, sorted, mean_bf, nullptr);
            sage_gemm_bf<true><<<512, 256, 0, stream>>>(xb, mean_bf, wT, bl, out);
        } else if (ws_size >= need_A2) {
            prep_bf<<<(N_NODES * D / 8 + 4096 + 255) / 256, 256, 0, stream>>>(x, Wl, Wr, xb, wT);
            sage_aggregate_bf<false><<<(N_NODES + 15) / 16, 256, 0, stream>>>(
                xb, ptr, sorted, nullptr, out);
            sage_gemm_bf<false><<<512, 256, 0, stream>>>(xb, nullptr, wT, bl, out);
        } else {
            unsigned short* wTc = (unsigned short*)cursor;   // cursor dead after fill
            wt_build<<<(128 * 256 + 255) / 256, 256, 0, stream>>>(Wl, Wr, wTc);
            sage_aggregate<<<(N_NODES + 3) / 4, 256, 0, stream>>>(x, ptr, sorted, out);
            sage_gemm_mfma<<<512, 256, 0, stream>>>(x, wTc, bl, out);
        }
    } else {
        float* deg = (float*)d_ws;
        hipMemsetAsync(out, 0, (size_t)N_NODES * D * sizeof(float), stream);
        hipMemsetAsync(deg, 0, (size_t)N_NODES * sizeof(float), stream);
        long long total = (long long)N_EDGES * 128;
        sage_scatter<<<(int)((total + 255) / 256), 256, 0, stream>>>(x, src, dst, out, deg);
        apply_mean<<<(N_NODES * 32 + 255) / 256, 256, 0, stream>>>(out, deg);
        sage_gemm_f32<<<512, 256, 0, stream>>>(x, Wl, bl, Wr, out);
    }
}

// Round 7
// 138.186 us; speedup vs baseline: 37.8384x; 1.0486x over previous
//
#include <hip/hip_runtime.h>

// SAGEConv: out = (mean_{j in N(i)} x_j) @ W_l + b_l + x_i @ W_r
// Inputs: x [N,128] f32, edge_index [2,E] int32, W_l [128,128] f32, b_l [128] f32, W_r [128,128] f32
// Output: [N,128] f32
//
// Path A: memset cnt -> prep_hist (x->bf16 + W^T bf16 + dst histogram)
//         -> scan -> add_offsets -> csr_fill -> gather-mean (16 lanes/node,
//         predicated 4-wide ILP) -> bf16 MFMA GEMM with register-resident B.
// Fallbacks: B (fp32 gather + convert-in-GEMM, LDS-B), C (atomic scatter).

constexpr int N_NODES = 100000;
constexpr int N_EDGES = 625000;
constexpr int D = 128;
constexpr int SCAN_CHUNK = 1024;
constexpr int N_SCAN_BLOCKS = (N_NODES + SCAN_CHUNK - 1) / SCAN_CHUNK;  // 98

typedef __attribute__((ext_vector_type(8))) short short8;
typedef __attribute__((ext_vector_type(4))) short short4v;
typedef __attribute__((ext_vector_type(4))) float f32x4;

__device__ __forceinline__ unsigned short f2bf(float f) {
    union { float f; unsigned int u; } c; c.f = f;
    unsigned int u = c.u + 0x7fffu + ((c.u >> 16) & 1u);   // RNE
    return (unsigned short)(u >> 16);
}
__device__ __forceinline__ float bflo(unsigned int v) {
    union { unsigned int u; float f; } c; c.u = v << 16; return c.f;
}
__device__ __forceinline__ float bfhi(unsigned int v) {
    union { unsigned int u; float f; } c; c.u = v & 0xffff0000u; return c.f;
}

// ============ fused prep: x->bf16, W^T bf16, dst histogram ============
__global__ __launch_bounds__(256) void prep_hist(
    const float* __restrict__ x, const float* __restrict__ Wl,
    const float* __restrict__ Wr, const int* __restrict__ dst,
    unsigned short* __restrict__ xb, unsigned short* __restrict__ wT,
    int* __restrict__ cnt)
{
    const int XC = N_NODES * D / 8;            // 1,600,000 short8 chunks
    int c = blockIdx.x * 256 + threadIdx.x;
    if (c < XC) {
        const float4* xp = (const float4*)x;
        float4 a = xp[(size_t)c * 2];
        float4 b = xp[(size_t)c * 2 + 1];
        short8 v;
        v[0] = (short)f2bf(a.x); v[1] = (short)f2bf(a.y);
        v[2] = (short)f2bf(a.z); v[3] = (short)f2bf(a.w);
        v[4] = (short)f2bf(b.x); v[5] = (short)f2bf(b.y);
        v[6] = (short)f2bf(b.z); v[7] = (short)f2bf(b.w);
        ((short8*)xb)[c] = v;
    } else if (c < XC + 4096) {                // 128*256/8 wT chunks
        int idx = c - XC;
        int n  = idx >> 5;
        int k0 = (idx & 31) * 8;
        short8 v;
        #pragma unroll
        for (int j = 0; j < 8; ++j) {
            int k = k0 + j;
            float f = (k < 128) ? Wl[k * 128 + n] : Wr[(k - 128) * 128 + n];
            v[j] = (short)f2bf(f);
        }
        *(short8*)&wT[n * 256 + k0] = v;
    } else if (c < XC + 4096 + N_EDGES) {      // histogram
        int e = c - XC - 4096;
        atomicAdd(&cnt[dst[e]], 1);
    }
}

// standalone histogram (Path B)
__global__ __launch_bounds__(256) void csr_hist(
    const int* __restrict__ dst, int* __restrict__ cnt)
{
    int e = blockIdx.x * 256 + threadIdx.x;
    if (e < N_EDGES) atomicAdd(&cnt[dst[e]], 1);
}

// ================= CSR scan / offsets / fill =================
__global__ __launch_bounds__(256) void scan_blocks(
    const int* __restrict__ cnt, int* __restrict__ ptr, int* __restrict__ bsums)
{
    __shared__ int sh[256];
    const int t = threadIdx.x;
    const int base = blockIdx.x * SCAN_CHUNK + t * 4;
    int v0 = (base + 0 < N_NODES) ? cnt[base + 0] : 0;
    int v1 = (base + 1 < N_NODES) ? cnt[base + 1] : 0;
    int v2 = (base + 2 < N_NODES) ? cnt[base + 2] : 0;
    int v3 = (base + 3 < N_NODES) ? cnt[base + 3] : 0;
    const int tsum = v0 + v1 + v2 + v3;
    sh[t] = tsum;
    __syncthreads();
    #pragma unroll
    for (int off = 1; off < 256; off <<= 1) {
        int val = (t >= off) ? sh[t - off] : 0;
        __syncthreads();
        sh[t] += val;
        __syncthreads();
    }
    const int texcl = sh[t] - tsum;
    if (t == 255) bsums[blockIdx.x] = sh[255];
    int e0 = texcl, e1 = e0 + v0, e2 = e1 + v1, e3 = e2 + v2;
    if (base + 0 < N_NODES) ptr[base + 0] = e0;
    if (base + 1 < N_NODES) ptr[base + 1] = e1;
    if (base + 2 < N_NODES) ptr[base + 2] = e2;
    if (base + 3 < N_NODES) ptr[base + 3] = e3;
}

__global__ __launch_bounds__(256) void add_offsets_fused(
    int* __restrict__ ptr, int* __restrict__ cursor, const int* __restrict__ bsums)
{
    __shared__ int sh[256];
    const int t = threadIdx.x;
    int v = (t < blockIdx.x) ? bsums[t] : 0;   // blockIdx.x <= 97 < 256
    sh[t] = v;
    __syncthreads();
    #pragma unroll
    for (int off = 128; off > 0; off >>= 1) {
        if (t < off) sh[t] += sh[t + off];
        __syncthreads();
    }
    const int soff = sh[0];
    const int base = blockIdx.x * SCAN_CHUNK + t * 4;
    #pragma unroll
    for (int j = 0; j < 4; ++j) {
        int i = base + j;
        if (i < N_NODES) {
            int p = ptr[i] + soff;
            ptr[i] = p;
            cursor[i] = p;
        }
    }
    if (blockIdx.x == 0 && t == 0) ptr[N_NODES] = N_EDGES;
}

__global__ __launch_bounds__(256) void csr_fill(
    const int* __restrict__ src, const int* __restrict__ dst,
    int* __restrict__ cursor, int* __restrict__ sorted_src)
{
    int e = blockIdx.x * 256 + threadIdx.x;
    if (e < N_EDGES) {
        int t = dst[e];
        int pos = atomicAdd(&cursor[t], 1);
        sorted_src[pos] = src[e];
    }
}

// ====== gather-mean: 16 lanes/node, predicated 4-wide (no serial tail) ======
template<bool MBF>
__global__ __launch_bounds__(256) void sage_aggregate_bf(
    const unsigned short* __restrict__ xb,
    const int* __restrict__ ptr,
    const int* __restrict__ sorted_src,
    unsigned short* __restrict__ mean_bf,
    float* __restrict__ mean_f32)
{
    const int node = blockIdx.x * 16 + (threadIdx.x >> 4);
    if (node >= N_NODES) return;
    const int l = threadIdx.x & 15;
    const int beg = ptr[node];
    const int end = ptr[node + 1];
    const size_t off = (size_t)l * 8;          // 8 bf16 = 16B per lane

    float a0=0,a1=0,a2=0,a3=0,a4=0,a5=0,a6=0,a7=0;
    float b0=0,b1=0,b2=0,b3=0,b4=0,b5=0,b6=0,b7=0;
    float c0=0,c1=0,c2=0,c3=0,c4=0,c5=0,c6=0,c7=0;
    float d0=0,d1=0,d2=0,d3=0,d4=0,d5=0,d6=0,d7=0;

    for (int i = beg; i < end; i += 4) {
        int last = end - 1;
        int e1 = i + 1 < end ? i + 1 : last;
        int e2 = i + 2 < end ? i + 2 : last;
        int e3 = i + 3 < end ? i + 3 : last;
        float w1 = (i + 1 < end) ? 1.f : 0.f;
        float w2 = (i + 2 < end) ? 1.f : 0.f;
        float w3 = (i + 3 < end) ? 1.f : 0.f;
        int s0 = sorted_src[i],  s1 = sorted_src[e1];
        int s2 = sorted_src[e2], s3 = sorted_src[e3];
        uint4 v0 = *(const uint4*)&xb[(size_t)s0 * D + off];
        uint4 v1 = *(const uint4*)&xb[(size_t)s1 * D + off];
        uint4 v2 = *(const uint4*)&xb[(size_t)s2 * D + off];
        uint4 v3 = *(const uint4*)&xb[(size_t)s3 * D + off];
        a0+=bflo(v0.x); a1+=bfhi(v0.x); a2+=bflo(v0.y); a3+=bfhi(v0.y);
        a4+=bflo(v0.z); a5+=bfhi(v0.z); a6+=bflo(v0.w); a7+=bfhi(v0.w);
        b0=fmaf(w1,bflo(v1.x),b0); b1=fmaf(w1,bfhi(v1.x),b1);
        b2=fmaf(w1,bflo(v1.y),b2); b3=fmaf(w1,bfhi(v1.y),b3);
        b4=fmaf(w1,bflo(v1.z),b4); b5=fmaf(w1,bfhi(v1.z),b5);
        b6=fmaf(w1,bflo(v1.w),b6); b7=fmaf(w1,bfhi(v1.w),b7);
        c0=fmaf(w2,bflo(v2.x),c0); c1=fmaf(w2,bfhi(v2.x),c1);
        c2=fmaf(w2,bflo(v2.y),c2); c3=fmaf(w2,bfhi(v2.y),c3);
        c4=fmaf(w2,bflo(v2.z),c4); c5=fmaf(w2,bfhi(v2.z),c5);
        c6=fmaf(w2,bflo(v2.w),c6); c7=fmaf(w2,bfhi(v2.w),c7);
        d0=fmaf(w3,bflo(v3.x),d0); d1=fmaf(w3,bfhi(v3.x),d1);
        d2=fmaf(w3,bflo(v3.y),d2); d3=fmaf(w3,bfhi(v3.y),d3);
        d4=fmaf(w3,bflo(v3.z),d4); d5=fmaf(w3,bfhi(v3.z),d5);
        d6=fmaf(w3,bflo(v3.w),d6); d7=fmaf(w3,bfhi(v3.w),d7);
    }
    const float sc = 1.0f / fmaxf((float)(end - beg), 1.0f);
    float r0 = ((a0+b0)+(c0+d0))*sc, r1 = ((a1+b1)+(c1+d1))*sc;
    float r2 = ((a2+b2)+(c2+d2))*sc, r3 = ((a3+b3)+(c3+d3))*sc;
    float r4 = ((a4+b4)+(c4+d4))*sc, r5 = ((a5+b5)+(c5+d5))*sc;
    float r6 = ((a6+b6)+(c6+d6))*sc, r7 = ((a7+b7)+(c7+d7))*sc;

    if constexpr (MBF) {
        uint4 o;
        o.x = (unsigned)f2bf(r0) | ((unsigned)f2bf(r1) << 16);
        o.y = (unsigned)f2bf(r2) | ((unsigned)f2bf(r3) << 16);
        o.z = (unsigned)f2bf(r4) | ((unsigned)f2bf(r5) << 16);
        o.w = (unsigned)f2bf(r6) | ((unsigned)f2bf(r7) << 16);
        *(uint4*)&mean_bf[(size_t)node * D + off] = o;
    } else {
        *(float4*)&mean_f32[(size_t)node * D + off] = make_float4(r0, r1, r2, r3);
        *(float4*)&mean_f32[(size_t)node * D + off + 4] = make_float4(r4, r5, r6, r7);
    }
}

// ========== bf16 MFMA GEMM, register-resident B (Path A) ==========
__global__ __launch_bounds__(256) void sage_gemm_rb(
    const unsigned short* __restrict__ xb,
    const unsigned short* __restrict__ mean_bf,
    const unsigned short* __restrict__ wT,
    const float* __restrict__ bl,
    float* __restrict__ out)
{
    __shared__ unsigned short sA[32 * 256];   // 16 KB

    const int tid  = threadIdx.x;
    const int lane = tid & 63;
    const int w    = tid >> 6;
    const int l15  = lane & 15;
    const int lg   = lane >> 4;

    const int n0 = w * 32 + l15;
    const int n1 = n0 + 16;

    short8 B0[8], B1[8];
    #pragma unroll
    for (int s = 0; s < 8; ++s) {
        B0[s] = *(const short8*)&wT[(size_t)n0 * 256 + s * 32 + lg * 8];
        B1[s] = *(const short8*)&wT[(size_t)n1 * 256 + s * 32 + lg * 8];
    }

    const int a_r0 = l15;
    const int a_r1 = 16 + l15;
    const float bias0 = bl[n0];
    const float bias1 = bl[n1];

    const int nTiles = N_NODES / 32;   // 3125, exact

    for (int tile = blockIdx.x; tile < nTiles; tile += gridDim.x) {
        const int row0 = tile * 32;

        #pragma unroll
        for (int i = 0; i < 4; ++i) {
            int c = tid + i * 256;
            int r = c >> 5;
            int s = c & 31;
            const unsigned short* srcp = (s < 16)
                ? &mean_bf[(size_t)(row0 + r) * D + s * 8]
                : &xb[(size_t)(row0 + r) * D + (s - 16) * 8];
            short8 v = *(const short8*)srcp;
            *(short8*)&sA[r * 256 + ((s ^ (r & 7)) << 3)] = v;
        }
        __syncthreads();

        f32x4 acc00 = {0.f,0.f,0.f,0.f}, acc01 = {0.f,0.f,0.f,0.f};
        f32x4 acc10 = {0.f,0.f,0.f,0.f}, acc11 = {0.f,0.f,0.f,0.f};

        #pragma unroll
        for (int s = 0; s < 8; ++s) {
            int ks = s * 4 + lg;
            short8 a0 = *(const short8*)&sA[a_r0 * 256 + ((ks ^ (a_r0 & 7)) << 3)];
            short8 a1 = *(const short8*)&sA[a_r1 * 256 + ((ks ^ (a_r1 & 7)) << 3)];
            acc00 = __builtin_amdgcn_mfma_f32_16x16x32_bf16(a0, B0[s], acc00, 0, 0, 0);
            acc01 = __builtin_amdgcn_mfma_f32_16x16x32_bf16(a0, B1[s], acc01, 0, 0, 0);
            acc10 = __builtin_amdgcn_mfma_f32_16x16x32_bf16(a1, B0[s], acc10, 0, 0, 0);
            acc11 = __builtin_amdgcn_mfma_f32_16x16x32_bf16(a1, B1[s], acc11, 0, 0, 0);
        }
        __syncthreads();

        #pragma unroll
        for (int reg = 0; reg < 4; ++reg) {
            int r0w = row0 + lg * 4 + reg;
            int r1w = r0w + 16;
            out[(size_t)r0w * D + n0] = acc00[reg] + bias0;
            out[(size_t)r0w * D + n1] = acc01[reg] + bias1;
            out[(size_t)r1w * D + n0] = acc10[reg] + bias0;
            out[(size_t)r1w * D + n1] = acc11[reg] + bias1;
        }
    }
}

// ================= Path B: fp32 gather + convert-in-GEMM (LDS-B) ===========
__global__ __launch_bounds__(256) void wt_build(
    const float* __restrict__ Wl, const float* __restrict__ Wr,
    unsigned short* __restrict__ wT)
{
    int idx = blockIdx.x * 256 + threadIdx.x;
    if (idx >= 128 * 256) return;
    int n = idx >> 8;
    int k = idx & 255;
    float v = (k < 128) ? Wl[k * 128 + n] : Wr[(k - 128) * 128 + n];
    wT[n * 256 + k] = f2bf(v);
}

__global__ __launch_bounds__(256) void sage_aggregate(
    const float* __restrict__ x,
    const int* __restrict__ ptr,
    const int* __restrict__ sorted_src,
    float* __restrict__ mean)
{
    const int node = blockIdx.x * 4 + (threadIdx.x >> 6);
    if (node >= N_NODES) return;
    const int lane = threadIdx.x & 63;
    const int beg = ptr[node];
    const int end = ptr[node + 1];

    float2 acc0 = make_float2(0.f, 0.f);
    float2 acc1 = make_float2(0.f, 0.f);
    int i = beg;
    for (; i + 1 < end; i += 2) {
        int s0 = sorted_src[i];
        int s1 = sorted_src[i + 1];
        float2 a = *(const float2*)&x[(size_t)s0 * D + lane * 2];
        float2 b = *(const float2*)&x[(size_t)s1 * D + lane * 2];
        acc0.x += a.x; acc0.y += a.y;
        acc1.x += b.x; acc1.y += b.y;
    }
    if (i < end) {
        int s0 = sorted_src[i];
        float2 a = *(const float2*)&x[(size_t)s0 * D + lane * 2];
        acc0.x += a.x; acc0.y += a.y;
    }
    const float sc = 1.0f / fmaxf((float)(end - beg), 1.0f);
    float2 r = make_float2((acc0.x + acc1.x) * sc, (acc0.y + acc1.y) * sc);
    *(float2*)&mean[(size_t)node * D + lane * 2] = r;
}

__global__ __launch_bounds__(256) void sage_gemm_mfma(
    const float* __restrict__ x,
    const unsigned short* __restrict__ wT,
    const float* __restrict__ bl,
    float* __restrict__ out)
{
    __shared__ unsigned short sW[128 * 256];
    __shared__ unsigned short sA[32 * 256];

    const int tid  = threadIdx.x;
    const int lane = tid & 63;
    const int w    = tid >> 6;
    const int l15  = lane & 15;
    const int lg   = lane >> 4;

    #pragma unroll
    for (int i = 0; i < 16; ++i) {
        int c  = tid + i * 256;
        int n  = c >> 5;
        int k8 = c & 31;
        short8 v = ((const short8*)wT)[c];
        *(short8*)&sW[n * 256 + ((k8 ^ (n & 7)) << 3)] = v;
    }

    const int a_r0 = l15;
    const int a_r1 = 16 + l15;
    const int n0 = w * 32 + l15;
    const int n1 = n0 + 16;
    const float bias0 = bl[n0];
    const float bias1 = bl[n1];
    const int nTiles = N_NODES / 32;

    for (int tile = blockIdx.x; tile < nTiles; tile += gridDim.x) {
        const int row0 = tile * 32;
        #pragma unroll
        for (int i = 0; i < 8; ++i) {
            int c    = tid + i * 256;
            int r    = c >> 6;
            int half = (c >> 5) & 1;
            int f4   = c & 31;
            const float* srcp = half ? &x[(size_t)(row0 + r) * D + f4 * 4]
                                     : &out[(size_t)(row0 + r) * D + f4 * 4];
            float4 v = *(const float4*)srcp;
            short4v b;
            b.x = (short)f2bf(v.x); b.y = (short)f2bf(v.y);
            b.z = (short)f2bf(v.z); b.w = (short)f2bf(v.w);
            int k = half * 128 + f4 * 4;
            int u = k >> 3;
            *(short4v*)&sA[r * 256 + ((u ^ (r & 7)) << 3) + (k & 7)] = b;
        }
        __syncthreads();

        f32x4 acc00 = {0.f,0.f,0.f,0.f}, acc01 = {0.f,0.f,0.f,0.f};
        f32x4 acc10 = {0.f,0.f,0.f,0.f}, acc11 = {0.f,0.f,0.f,0.f};

        #pragma unroll
        for (int s = 0; s < 8; ++s) {
            int ks = s * 4 + lg;
            short8 a0 = *(const short8*)&sA[a_r0 * 256 + ((ks ^ (a_r0 & 7)) << 3)];
            short8 a1 = *(const short8*)&sA[a_r1 * 256 + ((ks ^ (a_r1 & 7)) << 3)];
            short8 b0 = *(const short8*)&sW[n0 * 256 + ((ks ^ (n0 & 7)) << 3)];
            short8 b1 = *(const short8*)&sW[n1 * 256 + ((ks ^ (n1 & 7)) << 3)];
            acc00 = __builtin_amdgcn_mfma_f32_16x16x32_bf16(a0, b0, acc00, 0, 0, 0);
            acc01 = __builtin_amdgcn_mfma_f32_16x16x32_bf16(a0, b1, acc01, 0, 0, 0);
            acc10 = __builtin_amdgcn_mfma_f32_16x16x32_bf16(a1, b0, acc10, 0, 0, 0);
            acc11 = __builtin_amdgcn_mfma_f32_16x16x32_bf16(a1, b1, acc11, 0, 0, 0);
        }
        __syncthreads();

        #pragma unroll
        for (int reg = 0; reg < 4; ++reg) {
            int r0w = row0 + lg * 4 + reg;
            int r1w = r0w + 16;
            out[(size_t)r0w * D + n0] = acc00[reg] + bias0;
            out[(size_t)r0w * D + n1] = acc01[reg] + bias1;
            out[(size_t)r1w * D + n0] = acc10[reg] + bias0;
            out[(size_t)r1w * D + n1] = acc11[reg] + bias1;
        }
    }
}

// ================= Path C: scatter fallback ================================
__global__ __launch_bounds__(256) void sage_scatter(
    const float* __restrict__ x, const int* __restrict__ src,
    const int* __restrict__ dst, float* __restrict__ agg, float* __restrict__ deg)
{
    int gid = blockIdx.x * 256 + threadIdx.x;
    int e = gid >> 7;
    if (e >= N_EDGES) return;
    int d = gid & 127;
    atomicAdd(&agg[(size_t)dst[e] * D + d], x[(size_t)src[e] * D + d]);
    if (d == 0) atomicAdd(&deg[dst[e]], 1.0f);
}

__global__ __launch_bounds__(256) void apply_mean(
    float* __restrict__ agg, const float* __restrict__ deg)
{
    int gid = blockIdx.x * 256 + threadIdx.x;
    int row = gid >> 5;
    if (row >= N_NODES) return;
    float sc = 1.0f / fmaxf(deg[row], 1.0f);
    float4 v = ((float4*)agg)[gid];
    v.x *= sc; v.y *= sc; v.z *= sc; v.w *= sc;
    ((float4*)agg)[gid] = v;
}

__device__ __forceinline__ void accum_tile(
    float acc[4][4], const float (*sWf)[D], const float (*srow)[D], int h, int j4)
{
    #pragma unroll 2
    for (int k = 0; k < D; k += 4) {
        float4 w0 = *(const float4*)&sWf[k + 0][j4];
        float4 w1 = *(const float4*)&sWf[k + 1][j4];
        float4 w2 = *(const float4*)&sWf[k + 2][j4];
        float4 w3 = *(const float4*)&sWf[k + 3][j4];
        #pragma unroll
        for (int r = 0; r < 4; ++r) {
            float4 a = *(const float4*)&srow[h + r * 8][k];
            acc[r][0] = fmaf(a.x, w0.x, fmaf(a.y, w1.x, fmaf(a.z, w2.x, fmaf(a.w, w3.x, acc[r][0]))));
            acc[r][1] = fmaf(a.x, w0.y, fmaf(a.y, w1.y, fmaf(a.z, w2.y, fmaf(a.w, w3.y, acc[r][1]))));
            acc[r][2] = fmaf(a.x, w0.z, fmaf(a.y, w1.z, fmaf(a.z, w2.z, fmaf(a.w, w3.z, acc[r][2]))));
            acc[r][3] = fmaf(a.x, w0.w, fmaf(a.y, w1.w, fmaf(a.z, w2.w, fmaf(a.w, w3.w, acc[r][3]))));
        }
    }
}

__global__ __launch_bounds__(256) void sage_gemm_f32(
    const float* __restrict__ x, const float* __restrict__ Wl,
    const float* __restrict__ bl, const float* __restrict__ Wr,
    float* __restrict__ out)
{
    __shared__ float sWf[D][D];
    __shared__ float srow[32][D];
    const int tid = threadIdx.x;
    const int j4 = (tid & 31) * 4;
    const int h  = tid >> 5;
    const int nTiles = (N_NODES + 31) / 32;
    const float4 bias = *(const float4*)(bl + j4);

    for (int tile = blockIdx.x; tile < nTiles; tile += gridDim.x) {
        const int row0 = tile * 32;
        float acc[4][4];
        #pragma unroll
        for (int r = 0; r < 4; ++r)
            #pragma unroll
            for (int c = 0; c < 4; ++c) acc[r][c] = 0.0f;

        __syncthreads();
        #pragma unroll
        for (int i = 0; i < 16; ++i)
            ((float4*)sWf)[tid + i * 256] = ((const float4*)Wl)[tid + i * 256];
        #pragma unroll
        for (int i = 0; i < 4; ++i) {
            int idx = tid + i * 256, r = idx >> 5, c = idx & 31, row = row0 + r;
            float4 v = make_float4(0.f,0.f,0.f,0.f);
            if (row < N_NODES) v = ((const float4*)out)[(size_t)row * 32 + c];
            ((float4*)srow)[idx] = v;
        }
        __syncthreads();
        accum_tile(acc, sWf, srow, h, j4);

        __syncthreads();
        #pragma unroll
        for (int i = 0; i < 16; ++i)
            ((float4*)sWf)[tid + i * 256] = ((const float4*)Wr)[tid + i * 256];
        #pragma unroll
        for (int i = 0; i < 4; ++i) {
            int idx = tid + i * 256, r = idx >> 5, c = idx & 31, row = row0 + r;
            float4 v = make_float4(0.f,0.f,0.f,0.f);
            if (row < N_NODES) v = ((const float4*)x)[(size_t)row * 32 + c];
            ((float4*)srow)[idx] = v;
        }
        __syncthreads();
        accum_tile(acc, sWf, srow, h, j4);

        #pragma unroll
        for (int r = 0; r < 4; ++r) {
            int row = row0 + h + r * 8;
            if (row < N_NODES) {
                float4 v = make_float4(acc[r][0] + bias.x, acc[r][1] + bias.y,
                                       acc[r][2] + bias.z, acc[r][3] + bias.w);
                *(float4*)(out + (size_t)row * D + j4) = v;
            }
        }
    }
}

extern "C" void kernel_launch(void* const* d_in, const int* in_sizes, int n_in,
                              void* d_out, int out_size, void* d_ws, size_t ws_size,
                              hipStream_t stream) {
    const float* x   = (const float*)d_in[0];
    const int*   ei  = (const int*)d_in[1];
    const float* Wl  = (const float*)d_in[2];
    const float* bl  = (const float*)d_in[3];
    const float* Wr  = (const float*)d_in[4];
    float* out = (float*)d_out;

    const int* src = ei;
    const int* dst = ei + N_EDGES;

    int* cnt    = (int*)d_ws;                    // N
    int* ptr    = cnt + N_NODES;                 // N+1
    int* cursor = ptr + N_NODES + 1;             // N
    int* bsums  = cursor + N_NODES;              // 128
    int* sorted = bsums + 128;                   // E
    size_t int_count = (size_t)(3 * N_NODES + 1 + 128 + N_EDGES);
    int_count = (int_count + 7) & ~(size_t)7;    // 32B-align what follows
    unsigned short* wT      = (unsigned short*)((int*)d_ws + int_count); // 128*256 bf16
    unsigned short* xb      = wT + 128 * 256;                            // N*D bf16
    unsigned short* mean_bf = xb + (size_t)N_NODES * D;                  // N*D bf16

    size_t need_B  = int_count * sizeof(int);
    size_t need_A  = need_B + 128 * 256 * 2 + 2 * (size_t)N_NODES * D * 2;

    if (ws_size >= need_A) {
        hipMemsetAsync(cnt, 0, (size_t)N_NODES * sizeof(int), stream);
        const int PREP_TOTAL = N_NODES * D / 8 + 4096 + N_EDGES;
        prep_hist<<<(PREP_TOTAL + 255) / 256, 256, 0, stream>>>(
            x, Wl, Wr, dst, xb, wT, cnt);
        scan_blocks<<<N_SCAN_BLOCKS, 256, 0, stream>>>(cnt, ptr, bsums);
        add_offsets_fused<<<N_SCAN_BLOCKS, 256, 0, stream>>>(ptr, cursor, bsums);
        csr_fill<<<(N_EDGES + 255) / 256, 256, 0, stream>>>(src, dst, cursor, sorted);
        sage_aggregate_bf<true><<<(N_NODES + 15) / 16, 256, 0, stream>>>(
            xb, ptr, sorted, mean_bf, nullptr);
        sage_gemm_rb<<<768, 256, 0, stream>>>(xb, mean_bf, wT, bl, out);
    } else if (ws_size >= need_B) {
        hipMemsetAsync(cnt, 0, (size_t)N_NODES * sizeof(int), stream);
        csr_hist<<<(N_EDGES + 255) / 256, 256, 0, stream>>>(dst, cnt);
        scan_blocks<<<N_SCAN_BLOCKS, 256, 0, stream>>>(cnt, ptr, bsums);
        add_offsets_fused<<<N_SCAN_BLOCKS, 256, 0, stream>>>(ptr, cursor, bsums);
        csr_fill<<<(N_EDGES + 255) / 256, 256, 0, stream>>>(src, dst, cursor, sorted);
        unsigned short* wTc = (unsigned short*)cursor;   // cursor dead after fill
        wt_build<<<(128 * 256 + 255) / 256, 256, 0, stream>>>(Wl, Wr, wTc);
        sage_aggregate<<<(N_NODES + 3) / 4, 256, 0, stream>>>(x, ptr, sorted, out);
        sage_gemm_mfma<<<512, 256, 0, stream>>>(x, wTc, bl, out);
    } else {
        float* deg = (float*)d_ws;
        hipMemsetAsync(out, 0, (size_t)N_NODES * D * sizeof(float), stream);
        hipMemsetAsync(deg, 0, (size_t)N_NODES * sizeof(float), stream);
        long long total = (long long)N_EDGES * 128;
        sage_scatter<<<(int)((total + 255) / 256), 256, 0, stream>>>(x, src, dst, out, deg);
        apply_mean<<<(N_NODES * 32 + 255) / 256, 256, 0, stream>>>(out, deg);
        sage_gemm_f32<<<512, 256, 0, stream>>>(x, Wl, bl, Wr, out);
    }
}